// Round 1
// baseline (1911.831 us; speedup 1.0000x reference)
//
#include <hip/hip_runtime.h>
#include <hip/hip_bf16.h>

#define NN 50000
#define EE 800000
#define GG 512
#define HH 256
#define TT 32
#define LL 4
#define EPSF 1e-5f

// ---------------- degree / dinv ----------------
__global__ void k_degree(const int* __restrict__ dst, int* __restrict__ cnt, int E) {
    int e = blockIdx.x * 256 + threadIdx.x;
    if (e < E) atomicAdd(&cnt[dst[e]], 1);
}

__global__ void k_dinv(const int* __restrict__ cnt, float* __restrict__ dinv, int N) {
    int i = blockIdx.x * 256 + threadIdx.x;
    if (i < N) dinv[i] = rsqrtf((float)cnt[i] + 1.0f);
}

// ---------------- scan (3-phase, 1024/block) ----------------
__global__ void k_scan1(const int* __restrict__ cnt, int* __restrict__ incl,
                        int* __restrict__ bsum, int N) {
    __shared__ int s[1024];
    int i = blockIdx.x * 1024 + threadIdx.x;
    int v = (i < N) ? cnt[i] : 0;
    s[threadIdx.x] = v;
    __syncthreads();
    for (int off = 1; off < 1024; off <<= 1) {
        int t = (threadIdx.x >= off) ? s[threadIdx.x - off] : 0;
        __syncthreads();
        s[threadIdx.x] += t;
        __syncthreads();
    }
    if (i < N) incl[i] = s[threadIdx.x];
    if (threadIdx.x == 1023) bsum[blockIdx.x] = s[1023];
}

__global__ void k_scan2(int* __restrict__ bsum, int nb) {
    __shared__ int s[64];
    int v = (threadIdx.x < nb) ? bsum[threadIdx.x] : 0;
    s[threadIdx.x] = v;
    __syncthreads();
    for (int off = 1; off < 64; off <<= 1) {
        int t = (threadIdx.x >= off) ? s[threadIdx.x - off] : 0;
        __syncthreads();
        s[threadIdx.x] += t;
        __syncthreads();
    }
    if (threadIdx.x < nb) bsum[threadIdx.x] = s[threadIdx.x] - v;  // exclusive
}

__global__ void k_scan3(int* __restrict__ rs, const int* __restrict__ cnt,
                        const int* __restrict__ boff, int N) {
    int i = blockIdx.x * 256 + threadIdx.x;
    if (i < N) rs[i] = rs[i] + boff[i >> 10] - cnt[i];  // exclusive prefix
}

__global__ void k_scatter(const int* __restrict__ src, const int* __restrict__ dst,
                          const int* __restrict__ rs, int* __restrict__ cur,
                          int* __restrict__ csr, int E) {
    int e = blockIdx.x * 256 + threadIdx.x;
    if (e >= E) return;
    int d = dst[e];
    int p = rs[d] + atomicAdd(&cur[d], 1);
    csr[p] = src[e];
}

// ---------------- tiny projection: atom_proj (100x256) + tag_proj (3x256) ----------------
__global__ void k_proj(const float* __restrict__ atom_emb, const float* __restrict__ tag_emb,
                       const float* __restrict__ Wp, const float* __restrict__ bp,
                       float* __restrict__ aref, float* __restrict__ tref) {
    int r = blockIdx.x;
    int j = threadIdx.x;  // 256
    if (r < 100) {
        float acc = bp[j];
        for (int k = 0; k < HH; ++k) acc += atom_emb[r * HH + k] * Wp[(size_t)k * HH + j];
        aref[r * HH + j] = acc;
    } else {
        int tr = r - 100;
        float acc = 0.f;
        for (int k = 0; k < TT; ++k) acc += tag_emb[tr * TT + k] * Wp[(size_t)(HH + k) * HH + j];
        tref[tr * HH + j] = acc;
    }
}

__global__ void k_h0(const int* __restrict__ x, const int* __restrict__ tags,
                     const float* __restrict__ aref, const float* __restrict__ tref,
                     float* __restrict__ h, int N) {
    int n = blockIdx.x;
    int lane = threadIdx.x;  // 64
    float4 a = ((const float4*)(aref + (size_t)x[n] * HH))[lane];
    float4 t = ((const float4*)(tref + (size_t)tags[n] * HH))[lane];
    float4 r;
    r.x = a.x + t.x; r.y = a.y + t.y; r.z = a.z + t.z; r.w = a.w + t.w;
    ((float4*)(h + (size_t)n * HH))[lane] = r;
}

// ---------------- fp32 SGEMM: C[M,256] = A[M,256] @ B[256,256] ----------------
// 128x128 block tile, 256 threads, 8x8 microtile. B-fragment split (tx*4, 64+tx*4)
// keeps LDS b128 reads 2-way max (free).
#define GKC 16
__global__ __launch_bounds__(256) void k_gemm(const float* __restrict__ A,
                                              const float* __restrict__ B,
                                              float* __restrict__ C, int M) {
    __shared__ float As[GKC][128 + 4];
    __shared__ float Bs[GKC][128 + 4];
    int t = threadIdx.x;
    int tx = t & 15, ty = t >> 4;
    int row0 = blockIdx.y * 128, col0 = blockIdx.x * 128;
    float acc[8][8];
#pragma unroll
    for (int i = 0; i < 8; ++i)
#pragma unroll
        for (int j = 0; j < 8; ++j) acc[i][j] = 0.f;

    for (int k0 = 0; k0 < 256; k0 += GKC) {
        // stage A (128 rows x 16 k), transposed into As[k][row]
#pragma unroll
        for (int u = 0; u < 2; ++u) {
            int idx = t + u * 256;         // 0..511
            int r = idx >> 2;              // 0..127
            int kq = (idx & 3) << 2;       // 0,4,8,12
            int grow = row0 + r;
            float4 v = make_float4(0.f, 0.f, 0.f, 0.f);
            if (grow < M) v = *(const float4*)(A + (size_t)grow * 256 + k0 + kq);
            As[kq + 0][r] = v.x; As[kq + 1][r] = v.y;
            As[kq + 2][r] = v.z; As[kq + 3][r] = v.w;
        }
        // stage B (16 k x 128 cols)
#pragma unroll
        for (int u = 0; u < 2; ++u) {
            int idx = t + u * 256;
            int kk = idx >> 5;             // 0..15
            int j = (idx & 31) << 2;       // 0..124
            *(float4*)&Bs[kk][j] = *(const float4*)(B + (size_t)(k0 + kk) * 256 + col0 + j);
        }
        __syncthreads();
#pragma unroll
        for (int kk = 0; kk < GKC; ++kk) {
            float a[8], b[8];
            *(float4*)&a[0] = *(float4*)&As[kk][ty * 8];
            *(float4*)&a[4] = *(float4*)&As[kk][ty * 8 + 4];
            *(float4*)&b[0] = *(float4*)&Bs[kk][tx * 4];
            *(float4*)&b[4] = *(float4*)&Bs[kk][64 + tx * 4];
#pragma unroll
            for (int i = 0; i < 8; ++i)
#pragma unroll
                for (int j = 0; j < 8; ++j) acc[i][j] += a[i] * b[j];
        }
        __syncthreads();
    }
#pragma unroll
    for (int i = 0; i < 8; ++i) {
        int grow = row0 + ty * 8 + i;
        if (grow < M) {
            *(float4*)(C + (size_t)grow * 256 + col0 + tx * 4) =
                make_float4(acc[i][0], acc[i][1], acc[i][2], acc[i][3]);
            *(float4*)(C + (size_t)grow * 256 + col0 + 64 + tx * 4) =
                make_float4(acc[i][4], acc[i][5], acc[i][6], acc[i][7]);
        }
    }
}

// ---------------- CSR aggregation: one wave per node ----------------
__global__ void k_agg(const float* __restrict__ hw, float* __restrict__ agg,
                      const int* __restrict__ csr, const int* __restrict__ rs,
                      const int* __restrict__ cnt, const float* __restrict__ dinv,
                      const float* __restrict__ bias, int N) {
    int wave = threadIdx.x >> 6;
    int lane = threadIdx.x & 63;
    int n = blockIdx.x * 4 + wave;
    if (n >= N) return;
    float dn = dinv[n];
    int start = rs[n];
    int deg = cnt[n];
    float4 acc = ((const float4*)bias)[lane];
    // self-loop term
    float4 hv = ((const float4*)(hw + (size_t)n * HH))[lane];
    float sn = dn * dn;
    acc.x += hv.x * sn; acc.y += hv.y * sn; acc.z += hv.z * sn; acc.w += hv.w * sn;
    for (int e = 0; e < deg; ++e) {
        int s = csr[start + e];
        float c = dinv[s] * dn;
        float4 m = ((const float4*)(hw + (size_t)s * HH))[lane];
        acc.x += m.x * c; acc.y += m.y * c; acc.z += m.z * c; acc.w += m.w * c;
    }
    ((float4*)(agg + (size_t)n * HH))[lane] = acc;
}

// ---------------- BN stats (col sum / sumsq) ----------------
__global__ void k_bnstats(const float4* __restrict__ agg, float* __restrict__ colsum,
                          float* __restrict__ colsq, int N) {
    int lane = threadIdx.x;  // 64
    int rows_per = (N + gridDim.x - 1) / gridDim.x;
    int r0 = blockIdx.x * rows_per;
    int r1 = r0 + rows_per; if (r1 > N) r1 = N;
    float4 s = make_float4(0.f, 0.f, 0.f, 0.f);
    float4 s2 = make_float4(0.f, 0.f, 0.f, 0.f);
    for (int r = r0; r < r1; ++r) {
        float4 v = agg[(size_t)r * 64 + lane];
        s.x += v.x; s.y += v.y; s.z += v.z; s.w += v.w;
        s2.x += v.x * v.x; s2.y += v.y * v.y; s2.z += v.z * v.z; s2.w += v.w * v.w;
    }
    int j = lane * 4;
    atomicAdd(&colsum[j + 0], s.x); atomicAdd(&colsum[j + 1], s.y);
    atomicAdd(&colsum[j + 2], s.z); atomicAdd(&colsum[j + 3], s.w);
    atomicAdd(&colsq[j + 0], s2.x); atomicAdd(&colsq[j + 1], s2.y);
    atomicAdd(&colsq[j + 2], s2.z); atomicAdd(&colsq[j + 3], s2.w);
}

// ---------------- BN + ReLU + residual (in-place into h) ----------------
__global__ void k_epi(const float4* __restrict__ agg, float4* __restrict__ h,
                      const float4* __restrict__ colsum, const float4* __restrict__ colsq,
                      const float4* __restrict__ g4, const float4* __restrict__ b4,
                      int total, float invN) {
    int idx = blockIdx.x * 256 + threadIdx.x;
    if (idx >= total) return;
    int q = idx & 63;
    float4 a = agg[idx];
    float4 s = colsum[q], s2 = colsq[q], g = g4[q], b = b4[q];
    float4 hv = h[idx];
    float mu, var, v;
    mu = s.x * invN; var = s2.x * invN - mu * mu;
    v = (a.x - mu) * rsqrtf(var + EPSF) * g.x + b.x; hv.x += fmaxf(v, 0.f);
    mu = s.y * invN; var = s2.y * invN - mu * mu;
    v = (a.y - mu) * rsqrtf(var + EPSF) * g.y + b.y; hv.y += fmaxf(v, 0.f);
    mu = s.z * invN; var = s2.z * invN - mu * mu;
    v = (a.z - mu) * rsqrtf(var + EPSF) * g.z + b.z; hv.z += fmaxf(v, 0.f);
    mu = s.w * invN; var = s2.w * invN - mu * mu;
    v = (a.w - mu) * rsqrtf(var + EPSF) * g.w + b.w; hv.w += fmaxf(v, 0.f);
    h[idx] = hv;
}

// ---------------- global mean pool (atomics) ----------------
__global__ void k_pool(const float4* __restrict__ h, const int* __restrict__ batch,
                       float* __restrict__ psum, int* __restrict__ pcnt, int N) {
    int n = blockIdx.x;
    int lane = threadIdx.x;  // 64
    float4 v = h[(size_t)n * 64 + lane];
    int g = batch[n];
    float* base = psum + (size_t)g * HH + lane * 4;
    atomicAdd(base + 0, v.x); atomicAdd(base + 1, v.y);
    atomicAdd(base + 2, v.z); atomicAdd(base + 3, v.w);
    if (lane == 0) atomicAdd(&pcnt[g], 1);
}

// ---------------- MLP head: one block per graph ----------------
__global__ void k_head(const float* __restrict__ psum, const int* __restrict__ pcnt,
                       const float* __restrict__ W1, const float* __restrict__ b1,
                       const float* __restrict__ W2, const float* __restrict__ b2,
                       float* __restrict__ out) {
    __shared__ float prow[256];
    __shared__ float hred[128];
    int g = blockIdx.x, t = threadIdx.x;  // 128 threads
    int c = pcnt[g]; if (c < 1) c = 1;
    float inv = 1.0f / (float)c;
    prow[t] = psum[(size_t)g * HH + t] * inv;
    prow[t + 128] = psum[(size_t)g * HH + t + 128] * inv;
    __syncthreads();
    float acc = b1[t];
    for (int k = 0; k < HH; ++k) acc += prow[k] * W1[(size_t)k * 128 + t];
    float hid = fmaxf(acc, 0.f);
    hred[t] = hid * W2[t];
    __syncthreads();
    for (int off = 64; off > 0; off >>= 1) {
        if (t < off) hred[t] += hred[t + off];
        __syncthreads();
    }
    if (t == 0) out[g] = hred[0] + b2[0];
}

extern "C" void kernel_launch(void* const* d_in, const int* in_sizes, int n_in,
                              void* d_out, int out_size, void* d_ws, size_t ws_size,
                              hipStream_t stream) {
    const int* x        = (const int*)d_in[0];
    const int* tags     = (const int*)d_in[1];
    const int* ei       = (const int*)d_in[2];
    const int* batch    = (const int*)d_in[3];
    const float* atom_e = (const float*)d_in[4];
    const float* tag_e  = (const float*)d_in[5];
    const float* Wp     = (const float*)d_in[6];
    const float* bp     = (const float*)d_in[7];
    const float* gcn_W  = (const float*)d_in[8];
    const float* gcn_b  = (const float*)d_in[9];
    const float* bn_g   = (const float*)d_in[10];
    const float* bn_b   = (const float*)d_in[11];
    const float* W1     = (const float*)d_in[12];
    const float* b1     = (const float*)d_in[13];
    const float* W2     = (const float*)d_in[14];
    const float* b2     = (const float*)d_in[15];
    float* out = (float*)d_out;

    const int N = NN, E = EE, G = GG, H = HH;

    char* p = (char*)d_ws;
    auto alloc = [&](size_t bytes) {
        void* r = (void*)p;
        p += (bytes + 255) & ~(size_t)255;
        return r;
    };
    float* h    = (float*)alloc((size_t)N * H * 4);
    float* hw   = (float*)alloc((size_t)N * H * 4);
    float* agg  = (float*)alloc((size_t)N * H * 4);
    float* dinv = (float*)alloc((size_t)N * 4);
    int* cnt    = (int*)alloc((size_t)N * 4);
    int* rs     = (int*)alloc((size_t)N * 4);
    int* cur    = (int*)alloc((size_t)N * 4);
    int* csr    = (int*)alloc((size_t)E * 4);
    int* bsum   = (int*)alloc(64 * 4);
    float* aref = (float*)alloc(100 * (size_t)H * 4);
    float* tref = (float*)alloc(3 * (size_t)H * 4);
    float* cstat= (float*)alloc(2 * (size_t)H * 4);  // colsum | colsq
    float* psum = (float*)alloc((size_t)G * H * 4);
    int* pcnt   = (int*)alloc((size_t)G * 4);

    const int* src = ei;
    const int* dst = ei + E;

    hipMemsetAsync(cnt, 0, (size_t)N * 4, stream);
    hipMemsetAsync(cur, 0, (size_t)N * 4, stream);
    hipMemsetAsync(psum, 0, (size_t)G * H * 4, stream);
    hipMemsetAsync(pcnt, 0, (size_t)G * 4, stream);

    k_degree<<<(E + 255) / 256, 256, 0, stream>>>(dst, cnt, E);
    k_dinv<<<(N + 255) / 256, 256, 0, stream>>>(cnt, dinv, N);

    int nb = (N + 1023) / 1024;
    k_scan1<<<nb, 1024, 0, stream>>>(cnt, rs, bsum, N);
    k_scan2<<<1, 64, 0, stream>>>(bsum, nb);
    k_scan3<<<(N + 255) / 256, 256, 0, stream>>>(rs, cnt, bsum, N);
    k_scatter<<<(E + 255) / 256, 256, 0, stream>>>(src, dst, rs, cur, csr, E);

    k_proj<<<103, 256, 0, stream>>>(atom_e, tag_e, Wp, bp, aref, tref);
    k_h0<<<N, 64, 0, stream>>>(x, tags, aref, tref, h, N);

    for (int l = 0; l < LL; ++l) {
        k_gemm<<<dim3(2, (N + 127) / 128), 256, 0, stream>>>(h, gcn_W + (size_t)l * H * H, hw, N);
        k_agg<<<(N + 3) / 4, 256, 0, stream>>>(hw, agg, csr, rs, cnt, dinv, gcn_b + (size_t)l * H, N);
        hipMemsetAsync(cstat, 0, 2 * (size_t)H * 4, stream);
        k_bnstats<<<512, 64, 0, stream>>>((const float4*)agg, cstat, cstat + H, N);
        k_epi<<<(N * 64 + 255) / 256, 256, 0, stream>>>(
            (const float4*)agg, (float4*)h, (const float4*)cstat, (const float4*)(cstat + H),
            (const float4*)(bn_g + (size_t)l * H), (const float4*)(bn_b + (size_t)l * H),
            N * 64, 1.0f / (float)N);
    }

    k_pool<<<N, 64, 0, stream>>>((const float4*)h, batch, psum, pcnt, N);
    k_head<<<G, 128, 0, stream>>>(psum, pcnt, W1, b1, W2, b2, out);
}

// Round 2
// 1373.640 us; speedup vs baseline: 1.3918x; 1.3918x over previous
//
#include <hip/hip_runtime.h>
#include <hip/hip_bf16.h>

#define NN 50000
#define EE 800000
#define GG 512
#define HH 256
#define TT 32
#define LL 4
#define EPSF 1e-5f

// ---------- bf16 helpers ----------
__device__ inline unsigned short f2b(float f) {  // RNE
    unsigned u = __float_as_uint(f);
    unsigned r = (u + 0x7FFFu + ((u >> 16) & 1u)) >> 16;
    return (unsigned short)r;
}
__device__ inline float4 bf4_to_f4(ushort4 u) {
    float4 f;
    f.x = __uint_as_float((unsigned)u.x << 16);
    f.y = __uint_as_float((unsigned)u.y << 16);
    f.z = __uint_as_float((unsigned)u.z << 16);
    f.w = __uint_as_float((unsigned)u.w << 16);
    return f;
}

// ---------------- degree / dinv ----------------
__global__ void k_degree(const int* __restrict__ dst, int* __restrict__ cnt, int E) {
    int e = blockIdx.x * 256 + threadIdx.x;
    if (e < E) atomicAdd(&cnt[dst[e]], 1);
}

__global__ void k_dinv(const int* __restrict__ cnt, float* __restrict__ dinv, int N) {
    int i = blockIdx.x * 256 + threadIdx.x;
    if (i < N) dinv[i] = rsqrtf((float)cnt[i] + 1.0f);
}

// ---------------- scan (3-phase, 1024/block) ----------------
__global__ void k_scan1(const int* __restrict__ cnt, int* __restrict__ incl,
                        int* __restrict__ bsum, int N) {
    __shared__ int s[1024];
    int i = blockIdx.x * 1024 + threadIdx.x;
    int v = (i < N) ? cnt[i] : 0;
    s[threadIdx.x] = v;
    __syncthreads();
    for (int off = 1; off < 1024; off <<= 1) {
        int t = (threadIdx.x >= off) ? s[threadIdx.x - off] : 0;
        __syncthreads();
        s[threadIdx.x] += t;
        __syncthreads();
    }
    if (i < N) incl[i] = s[threadIdx.x];
    if (threadIdx.x == 1023) bsum[blockIdx.x] = s[1023];
}

__global__ void k_scan2(int* __restrict__ bsum, int nb) {
    __shared__ int s[64];
    int v = (threadIdx.x < nb) ? bsum[threadIdx.x] : 0;
    s[threadIdx.x] = v;
    __syncthreads();
    for (int off = 1; off < 64; off <<= 1) {
        int t = (threadIdx.x >= off) ? s[threadIdx.x - off] : 0;
        __syncthreads();
        s[threadIdx.x] += t;
        __syncthreads();
    }
    if (threadIdx.x < nb) bsum[threadIdx.x] = s[threadIdx.x] - v;  // exclusive
}

__global__ void k_scan3(int* __restrict__ rs, const int* __restrict__ cnt,
                        const int* __restrict__ boff, int N) {
    int i = blockIdx.x * 256 + threadIdx.x;
    if (i < N) rs[i] = rs[i] + boff[i >> 10] - cnt[i];  // exclusive prefix
}

__global__ void k_scatter(const int* __restrict__ src, const int* __restrict__ dst,
                          const int* __restrict__ rs, int* __restrict__ cur,
                          int* __restrict__ csr, int E) {
    int e = blockIdx.x * 256 + threadIdx.x;
    if (e >= E) return;
    int d = dst[e];
    int p = rs[d] + atomicAdd(&cur[d], 1);
    csr[p] = src[e];
}

// ---------------- tiny projection: atom_proj (100x256) + tag_proj (3x256) ----------------
__global__ void k_proj(const float* __restrict__ atom_emb, const float* __restrict__ tag_emb,
                       const float* __restrict__ Wp, const float* __restrict__ bp,
                       float* __restrict__ aref, float* __restrict__ tref) {
    int r = blockIdx.x;
    int j = threadIdx.x;  // 256
    if (r < 100) {
        float acc = bp[j];
        for (int k = 0; k < HH; ++k) acc += atom_emb[r * HH + k] * Wp[(size_t)k * HH + j];
        aref[r * HH + j] = acc;
    } else {
        int tr = r - 100;
        float acc = 0.f;
        for (int k = 0; k < TT; ++k) acc += tag_emb[tr * TT + k] * Wp[(size_t)(HH + k) * HH + j];
        tref[tr * HH + j] = acc;
    }
}

__global__ void k_h0(const int* __restrict__ x, const int* __restrict__ tags,
                     const float* __restrict__ aref, const float* __restrict__ tref,
                     float* __restrict__ h, int N) {
    int n = blockIdx.x;
    int lane = threadIdx.x;  // 64
    float4 a = ((const float4*)(aref + (size_t)x[n] * HH))[lane];
    float4 t = ((const float4*)(tref + (size_t)tags[n] * HH))[lane];
    float4 r;
    r.x = a.x + t.x; r.y = a.y + t.y; r.z = a.z + t.z; r.w = a.w + t.w;
    ((float4*)(h + (size_t)n * HH))[lane] = r;
}

// ---------------- fp32 SGEMM: hwb[M,256](bf16) = (A[M,256] @ B[256,256]) * dinv[row] ----------------
// 128x128 block tile, 256 threads, 8x8 microtile.
#define GKC 16
__global__ __launch_bounds__(256) void k_gemm(const float* __restrict__ A,
                                              const float* __restrict__ B,
                                              const float* __restrict__ dinv,
                                              unsigned short* __restrict__ hwb, int M) {
    __shared__ float As[GKC][128 + 4];
    __shared__ float Bs[GKC][128 + 4];
    int t = threadIdx.x;
    int tx = t & 15, ty = t >> 4;
    int row0 = blockIdx.y * 128, col0 = blockIdx.x * 128;
    float acc[8][8];
#pragma unroll
    for (int i = 0; i < 8; ++i)
#pragma unroll
        for (int j = 0; j < 8; ++j) acc[i][j] = 0.f;

    for (int k0 = 0; k0 < 256; k0 += GKC) {
#pragma unroll
        for (int u = 0; u < 2; ++u) {
            int idx = t + u * 256;         // 0..511
            int r = idx >> 2;              // 0..127
            int kq = (idx & 3) << 2;       // 0,4,8,12
            int grow = row0 + r;
            float4 v = make_float4(0.f, 0.f, 0.f, 0.f);
            if (grow < M) v = *(const float4*)(A + (size_t)grow * 256 + k0 + kq);
            As[kq + 0][r] = v.x; As[kq + 1][r] = v.y;
            As[kq + 2][r] = v.z; As[kq + 3][r] = v.w;
        }
#pragma unroll
        for (int u = 0; u < 2; ++u) {
            int idx = t + u * 256;
            int kk = idx >> 5;             // 0..15
            int j = (idx & 31) << 2;       // 0..124
            *(float4*)&Bs[kk][j] = *(const float4*)(B + (size_t)(k0 + kk) * 256 + col0 + j);
        }
        __syncthreads();
#pragma unroll
        for (int kk = 0; kk < GKC; ++kk) {
            float a[8], b[8];
            *(float4*)&a[0] = *(float4*)&As[kk][ty * 8];
            *(float4*)&a[4] = *(float4*)&As[kk][ty * 8 + 4];
            *(float4*)&b[0] = *(float4*)&Bs[kk][tx * 4];
            *(float4*)&b[4] = *(float4*)&Bs[kk][64 + tx * 4];
#pragma unroll
            for (int i = 0; i < 8; ++i)
#pragma unroll
                for (int j = 0; j < 8; ++j) acc[i][j] += a[i] * b[j];
        }
        __syncthreads();
    }
#pragma unroll
    for (int i = 0; i < 8; ++i) {
        int grow = row0 + ty * 8 + i;
        if (grow < M) {
            float dv = dinv[grow];
            ushort4 u0, u1;
            u0.x = f2b(acc[i][0] * dv); u0.y = f2b(acc[i][1] * dv);
            u0.z = f2b(acc[i][2] * dv); u0.w = f2b(acc[i][3] * dv);
            u1.x = f2b(acc[i][4] * dv); u1.y = f2b(acc[i][5] * dv);
            u1.z = f2b(acc[i][6] * dv); u1.w = f2b(acc[i][7] * dv);
            *(ushort4*)(hwb + (size_t)grow * 256 + col0 + tx * 4) = u0;
            *(ushort4*)(hwb + (size_t)grow * 256 + col0 + 64 + tx * 4) = u1;
        }
    }
}

// ---------------- CSR aggregation (bf16 gathers): one wave per node ----------------
// agg[n] = dinv[n] * ( sum_{e in in(n)} hwb[src_e] + hwb[n] ) + bias
// (hwb already carries dinv[src]; self term hw[n]*dinv^2 = hwb[n]*dinv[n])
__global__ void k_agg(const unsigned short* __restrict__ hwb, float* __restrict__ agg,
                      const int* __restrict__ csr, const int* __restrict__ rs,
                      const int* __restrict__ cnt, const float* __restrict__ dinv,
                      const float* __restrict__ bias, int N) {
    int wave = threadIdx.x >> 6;
    int lane = threadIdx.x & 63;
    int n = blockIdx.x * 4 + wave;
    if (n >= N) return;
    float dn = dinv[n];
    int start = rs[n];
    int deg = cnt[n];
    // self term
    float4 acc = bf4_to_f4(((const ushort4*)(hwb + (size_t)n * HH))[lane]);
    for (int e = 0; e < deg; ++e) {
        int s = csr[start + e];
        float4 m = bf4_to_f4(((const ushort4*)(hwb + (size_t)s * HH))[lane]);
        acc.x += m.x; acc.y += m.y; acc.z += m.z; acc.w += m.w;
    }
    float4 b = ((const float4*)bias)[lane];
    float4 r;
    r.x = acc.x * dn + b.x; r.y = acc.y * dn + b.y;
    r.z = acc.z * dn + b.z; r.w = acc.w * dn + b.w;
    ((float4*)(agg + (size_t)n * HH))[lane] = r;
}

// ---------------- BN stats (col sum / sumsq) ----------------
__global__ void k_bnstats(const float4* __restrict__ agg, float* __restrict__ colsum,
                          float* __restrict__ colsq, int N) {
    int lane = threadIdx.x;  // 64
    int rows_per = (N + gridDim.x - 1) / gridDim.x;
    int r0 = blockIdx.x * rows_per;
    int r1 = r0 + rows_per; if (r1 > N) r1 = N;
    float4 s = make_float4(0.f, 0.f, 0.f, 0.f);
    float4 s2 = make_float4(0.f, 0.f, 0.f, 0.f);
    for (int r = r0; r < r1; ++r) {
        float4 v = agg[(size_t)r * 64 + lane];
        s.x += v.x; s.y += v.y; s.z += v.z; s.w += v.w;
        s2.x += v.x * v.x; s2.y += v.y * v.y; s2.z += v.z * v.z; s2.w += v.w * v.w;
    }
    int j = lane * 4;
    atomicAdd(&colsum[j + 0], s.x); atomicAdd(&colsum[j + 1], s.y);
    atomicAdd(&colsum[j + 2], s.z); atomicAdd(&colsum[j + 3], s.w);
    atomicAdd(&colsq[j + 0], s2.x); atomicAdd(&colsq[j + 1], s2.y);
    atomicAdd(&colsq[j + 2], s2.z); atomicAdd(&colsq[j + 3], s2.w);
}

// ---------------- BN + ReLU + residual (in-place into h) ----------------
__global__ void k_epi(const float4* __restrict__ agg, float4* __restrict__ h,
                      const float4* __restrict__ colsum, const float4* __restrict__ colsq,
                      const float4* __restrict__ g4, const float4* __restrict__ b4,
                      int total, float invN) {
    int idx = blockIdx.x * 256 + threadIdx.x;
    if (idx >= total) return;
    int q = idx & 63;
    float4 a = agg[idx];
    float4 s = colsum[q], s2 = colsq[q], g = g4[q], b = b4[q];
    float4 hv = h[idx];
    float mu, var, v;
    mu = s.x * invN; var = s2.x * invN - mu * mu;
    v = (a.x - mu) * rsqrtf(var + EPSF) * g.x + b.x; hv.x += fmaxf(v, 0.f);
    mu = s.y * invN; var = s2.y * invN - mu * mu;
    v = (a.y - mu) * rsqrtf(var + EPSF) * g.y + b.y; hv.y += fmaxf(v, 0.f);
    mu = s.z * invN; var = s2.z * invN - mu * mu;
    v = (a.z - mu) * rsqrtf(var + EPSF) * g.z + b.z; hv.z += fmaxf(v, 0.f);
    mu = s.w * invN; var = s2.w * invN - mu * mu;
    v = (a.w - mu) * rsqrtf(var + EPSF) * g.w + b.w; hv.w += fmaxf(v, 0.f);
    h[idx] = hv;
}

// ---------------- graph boundaries (batch is sorted) ----------------
__global__ void k_ginit(int* __restrict__ gstart, int G, int N) {
    int g = blockIdx.x * 256 + threadIdx.x;
    if (g <= G) gstart[g] = N;
}

__global__ void k_gbound(const int* __restrict__ batch, int* __restrict__ gstart, int N) {
    int n = blockIdx.x * 256 + threadIdx.x;
    if (n >= N) return;
    int b = batch[n];
    int prev = (n == 0) ? -1 : batch[n - 1];
    for (int g = prev + 1; g <= b; ++g) gstart[g] = n;
}

// ---------------- segmented mean pool: one block (4 waves) per graph ----------------
__global__ void k_pool(const float4* __restrict__ h, const int* __restrict__ gstart,
                       float* __restrict__ pooled) {
    __shared__ float4 sm[4][64];
    int g = blockIdx.x;
    int t = threadIdx.x;
    int lane = t & 63, wv = t >> 6;
    int s = gstart[g], e = gstart[g + 1];
    float4 acc = make_float4(0.f, 0.f, 0.f, 0.f);
    for (int n = s + wv; n < e; n += 4) {
        float4 v = h[(size_t)n * 64 + lane];
        acc.x += v.x; acc.y += v.y; acc.z += v.z; acc.w += v.w;
    }
    sm[wv][lane] = acc;
    __syncthreads();
    if (wv == 0) {
        float4 a = sm[0][lane], b = sm[1][lane], c = sm[2][lane], d = sm[3][lane];
        float inv = 1.0f / fmaxf((float)(e - s), 1.0f);
        float4 r;
        r.x = (a.x + b.x + c.x + d.x) * inv;
        r.y = (a.y + b.y + c.y + d.y) * inv;
        r.z = (a.z + b.z + c.z + d.z) * inv;
        r.w = (a.w + b.w + c.w + d.w) * inv;
        ((float4*)pooled)[(size_t)g * 64 + lane] = r;
    }
}

// ---------------- MLP head: one block per graph ----------------
__global__ void k_head(const float* __restrict__ pooled,
                       const float* __restrict__ W1, const float* __restrict__ b1,
                       const float* __restrict__ W2, const float* __restrict__ b2,
                       float* __restrict__ out) {
    __shared__ float prow[256];
    __shared__ float hred[128];
    int g = blockIdx.x, t = threadIdx.x;  // 128 threads
    prow[t] = pooled[(size_t)g * HH + t];
    prow[t + 128] = pooled[(size_t)g * HH + t + 128];
    __syncthreads();
    float acc = b1[t];
    for (int k = 0; k < HH; ++k) acc += prow[k] * W1[(size_t)k * 128 + t];
    float hid = fmaxf(acc, 0.f);
    hred[t] = hid * W2[t];
    __syncthreads();
    for (int off = 64; off > 0; off >>= 1) {
        if (t < off) hred[t] += hred[t + off];
        __syncthreads();
    }
    if (t == 0) out[g] = hred[0] + b2[0];
}

extern "C" void kernel_launch(void* const* d_in, const int* in_sizes, int n_in,
                              void* d_out, int out_size, void* d_ws, size_t ws_size,
                              hipStream_t stream) {
    const int* x        = (const int*)d_in[0];
    const int* tags     = (const int*)d_in[1];
    const int* ei       = (const int*)d_in[2];
    const int* batch    = (const int*)d_in[3];
    const float* atom_e = (const float*)d_in[4];
    const float* tag_e  = (const float*)d_in[5];
    const float* Wp     = (const float*)d_in[6];
    const float* bp     = (const float*)d_in[7];
    const float* gcn_W  = (const float*)d_in[8];
    const float* gcn_b  = (const float*)d_in[9];
    const float* bn_g   = (const float*)d_in[10];
    const float* bn_b   = (const float*)d_in[11];
    const float* W1     = (const float*)d_in[12];
    const float* b1     = (const float*)d_in[13];
    const float* W2     = (const float*)d_in[14];
    const float* b2     = (const float*)d_in[15];
    float* out = (float*)d_out;

    const int N = NN, E = EE, G = GG, H = HH;

    char* p = (char*)d_ws;
    auto alloc = [&](size_t bytes) {
        void* r = (void*)p;
        p += (bytes + 255) & ~(size_t)255;
        return r;
    };
    float* h    = (float*)alloc((size_t)N * H * 4);
    unsigned short* hwb = (unsigned short*)alloc((size_t)N * H * 2);
    float* agg  = (float*)alloc((size_t)N * H * 4);
    float* dinv = (float*)alloc((size_t)N * 4);
    int* cnt    = (int*)alloc((size_t)N * 4);
    int* rs     = (int*)alloc((size_t)N * 4);
    int* cur    = (int*)alloc((size_t)N * 4);
    int* csr    = (int*)alloc((size_t)E * 4);
    int* bsum   = (int*)alloc(64 * 4);
    float* aref = (float*)alloc(100 * (size_t)H * 4);
    float* tref = (float*)alloc(3 * (size_t)H * 4);
    float* cstat= (float*)alloc(2 * (size_t)H * 4);  // colsum | colsq
    int* gstart = (int*)alloc((size_t)(G + 1) * 4);
    float* pooled = (float*)alloc((size_t)G * H * 4);

    const int* src = ei;
    const int* dst = ei + E;

    hipMemsetAsync(cnt, 0, (size_t)N * 4, stream);
    hipMemsetAsync(cur, 0, (size_t)N * 4, stream);

    k_degree<<<(E + 255) / 256, 256, 0, stream>>>(dst, cnt, E);
    k_dinv<<<(N + 255) / 256, 256, 0, stream>>>(cnt, dinv, N);

    int nb = (N + 1023) / 1024;
    k_scan1<<<nb, 1024, 0, stream>>>(cnt, rs, bsum, N);
    k_scan2<<<1, 64, 0, stream>>>(bsum, nb);
    k_scan3<<<(N + 255) / 256, 256, 0, stream>>>(rs, cnt, bsum, N);
    k_scatter<<<(E + 255) / 256, 256, 0, stream>>>(src, dst, rs, cur, csr, E);

    k_ginit<<<(G + 256) / 256, 256, 0, stream>>>(gstart, G, N);
    k_gbound<<<(N + 255) / 256, 256, 0, stream>>>(batch, gstart, N);

    k_proj<<<103, 256, 0, stream>>>(atom_e, tag_e, Wp, bp, aref, tref);
    k_h0<<<N, 64, 0, stream>>>(x, tags, aref, tref, h, N);

    for (int l = 0; l < LL; ++l) {
        k_gemm<<<dim3(2, (N + 127) / 128), 256, 0, stream>>>(
            h, gcn_W + (size_t)l * H * H, dinv, hwb, N);
        k_agg<<<(N + 3) / 4, 256, 0, stream>>>(hwb, agg, csr, rs, cnt, dinv,
                                               gcn_b + (size_t)l * H, N);
        hipMemsetAsync(cstat, 0, 2 * (size_t)H * 4, stream);
        k_bnstats<<<512, 64, 0, stream>>>((const float4*)agg, cstat, cstat + H, N);
        k_epi<<<(N * 64 + 255) / 256, 256, 0, stream>>>(
            (const float4*)agg, (float4*)h, (const float4*)cstat, (const float4*)(cstat + H),
            (const float4*)(bn_g + (size_t)l * H), (const float4*)(bn_b + (size_t)l * H),
            N * 64, 1.0f / (float)N);
    }

    k_pool<<<G, 256, 0, stream>>>((const float4*)h, gstart, pooled);
    k_head<<<G, 128, 0, stream>>>(pooled, W1, b1, W2, b2, out);
}

// Round 3
// 996.549 us; speedup vs baseline: 1.9185x; 1.3784x over previous
//
#include <hip/hip_runtime.h>
#include <hip/hip_bf16.h>

#define NN 50000
#define EE 800000
#define GG 512
#define HH 256
#define TT 32
#define LL 4
#define EPSF 1e-5f

typedef __attribute__((ext_vector_type(8))) short short8;
typedef __attribute__((ext_vector_type(4))) float float4v;

// ---------- bf16 helpers ----------
__device__ inline unsigned short f2b(float f) {  // RNE
    unsigned u = __float_as_uint(f);
    unsigned r = (u + 0x7FFFu + ((u >> 16) & 1u)) >> 16;
    return (unsigned short)r;
}
__device__ inline float4 bf4_to_f4(ushort4 u) {
    float4 f;
    f.x = __uint_as_float((unsigned)u.x << 16);
    f.y = __uint_as_float((unsigned)u.y << 16);
    f.z = __uint_as_float((unsigned)u.z << 16);
    f.w = __uint_as_float((unsigned)u.w << 16);
    return f;
}

// ---------------- degree / dinv ----------------
__global__ void k_degree(const int* __restrict__ dst, int* __restrict__ cnt, int E) {
    int e = blockIdx.x * 256 + threadIdx.x;
    if (e < E) atomicAdd(&cnt[dst[e]], 1);
}

__global__ void k_dinv(const int* __restrict__ cnt, float* __restrict__ dinv, int N) {
    int i = blockIdx.x * 256 + threadIdx.x;
    if (i < N) dinv[i] = rsqrtf((float)cnt[i] + 1.0f);
}

// ---------------- scan (3-phase, 1024/block) ----------------
__global__ void k_scan1(const int* __restrict__ cnt, int* __restrict__ incl,
                        int* __restrict__ bsum, int N) {
    __shared__ int s[1024];
    int i = blockIdx.x * 1024 + threadIdx.x;
    int v = (i < N) ? cnt[i] : 0;
    s[threadIdx.x] = v;
    __syncthreads();
    for (int off = 1; off < 1024; off <<= 1) {
        int t = (threadIdx.x >= off) ? s[threadIdx.x - off] : 0;
        __syncthreads();
        s[threadIdx.x] += t;
        __syncthreads();
    }
    if (i < N) incl[i] = s[threadIdx.x];
    if (threadIdx.x == 1023) bsum[blockIdx.x] = s[1023];
}

__global__ void k_scan2(int* __restrict__ bsum, int nb) {
    __shared__ int s[64];
    int v = (threadIdx.x < nb) ? bsum[threadIdx.x] : 0;
    s[threadIdx.x] = v;
    __syncthreads();
    for (int off = 1; off < 64; off <<= 1) {
        int t = (threadIdx.x >= off) ? s[threadIdx.x - off] : 0;
        __syncthreads();
        s[threadIdx.x] += t;
        __syncthreads();
    }
    if (threadIdx.x < nb) bsum[threadIdx.x] = s[threadIdx.x] - v;  // exclusive
}

__global__ void k_scan3(int* __restrict__ rs, const int* __restrict__ cnt,
                        const int* __restrict__ boff, int N) {
    int i = blockIdx.x * 256 + threadIdx.x;
    if (i < N) rs[i] = rs[i] + boff[i >> 10] - cnt[i];  // exclusive prefix
}

__global__ void k_scatter(const int* __restrict__ src, const int* __restrict__ dst,
                          const int* __restrict__ rs, int* __restrict__ cur,
                          int* __restrict__ csr, int E) {
    int e = blockIdx.x * 256 + threadIdx.x;
    if (e >= E) return;
    int d = dst[e];
    int p = rs[d] + atomicAdd(&cur[d], 1);
    csr[p] = src[e];
}

// ---------------- weight prep: Wt[l][n][k] bf16 ----------------
__global__ void k_wprep(const float* __restrict__ W, unsigned short* __restrict__ Wt) {
    int l = blockIdx.y;
    int n = blockIdx.x * 4 + (threadIdx.x >> 6);
    int kq = (threadIdx.x & 63) * 4;
    const float* Wl = W + (size_t)l * HH * HH;
    ushort4 o;
    o.x = f2b(Wl[(size_t)(kq + 0) * HH + n]);
    o.y = f2b(Wl[(size_t)(kq + 1) * HH + n]);
    o.z = f2b(Wl[(size_t)(kq + 2) * HH + n]);
    o.w = f2b(Wl[(size_t)(kq + 3) * HH + n]);
    *(ushort4*)(Wt + (size_t)l * HH * HH + (size_t)n * HH + kq) = o;
}

// ---------------- tiny projection: atom_proj (100x256) + tag_proj (3x256) ----------------
__global__ void k_proj(const float* __restrict__ atom_emb, const float* __restrict__ tag_emb,
                       const float* __restrict__ Wp, const float* __restrict__ bp,
                       float* __restrict__ aref, float* __restrict__ tref) {
    int r = blockIdx.x;
    int j = threadIdx.x;  // 256
    if (r < 100) {
        float acc = bp[j];
        for (int k = 0; k < HH; ++k) acc += atom_emb[r * HH + k] * Wp[(size_t)k * HH + j];
        aref[r * HH + j] = acc;
    } else {
        int tr = r - 100;
        float acc = 0.f;
        for (int k = 0; k < TT; ++k) acc += tag_emb[tr * TT + k] * Wp[(size_t)(HH + k) * HH + j];
        tref[tr * HH + j] = acc;
    }
}

__global__ void k_h0(const int* __restrict__ x, const int* __restrict__ tags,
                     const float* __restrict__ aref, const float* __restrict__ tref,
                     float* __restrict__ h, unsigned short* __restrict__ hb, int N) {
    int n = blockIdx.x;
    int lane = threadIdx.x;  // 64
    float4 a = ((const float4*)(aref + (size_t)x[n] * HH))[lane];
    float4 t = ((const float4*)(tref + (size_t)tags[n] * HH))[lane];
    float4 r;
    r.x = a.x + t.x; r.y = a.y + t.y; r.z = a.z + t.z; r.w = a.w + t.w;
    ((float4*)(h + (size_t)n * HH))[lane] = r;
    ushort4 u;
    u.x = f2b(r.x); u.y = f2b(r.y); u.z = f2b(r.z); u.w = f2b(r.w);
    ((ushort4*)(hb + (size_t)n * HH))[lane] = u;
}

// ---------------- MFMA bf16 GEMM: hwb[M,256] = bf16( (hb @ Wt^T) * dinv[row] ) ----------------
// 128x128 tile, 4 waves (each 64x64), BK=64, 16x16x32 MFMA, fp32 accum.
// LDS rows padded +8 bf16 so ds_read_b128 banks distribute evenly.
__global__ __launch_bounds__(256) void k_gemm(const unsigned short* __restrict__ hb,
                                              const unsigned short* __restrict__ Wt,
                                              const float* __restrict__ dinv,
                                              unsigned short* __restrict__ hwb, int M) {
    __shared__ unsigned short As[128][72];
    __shared__ unsigned short Bs[128][72];
    int t = threadIdx.x;
    int lane = t & 63, w = t >> 6;
    int wr = w >> 1, wc = w & 1;
    int l15 = lane & 15, l4 = lane >> 4;
    int row0 = blockIdx.y * 128, col0 = blockIdx.x * 128;
    float4v acc[4][4];
#pragma unroll
    for (int i = 0; i < 4; ++i)
#pragma unroll
        for (int j = 0; j < 4; ++j) acc[i][j] = (float4v)0.f;

    for (int k0 = 0; k0 < 256; k0 += 64) {
        if (k0) __syncthreads();
#pragma unroll
        for (int u = 0; u < 4; ++u) {
            int idx = u * 256 + t;          // 0..1023
            int r = idx >> 3;               // 0..127
            int c = (idx & 7) * 8;          // bf16 col
            *(uint4*)&As[r][c] = *(const uint4*)(hb + (size_t)(row0 + r) * 256 + k0 + c);
            *(uint4*)&Bs[r][c] = *(const uint4*)(Wt + (size_t)(col0 + r) * 256 + k0 + c);
        }
        __syncthreads();
#pragma unroll
        for (int kk = 0; kk < 64; kk += 32) {
            short8 a[4], b[4];
#pragma unroll
            for (int i = 0; i < 4; ++i)
                a[i] = *(const short8*)&As[wr * 64 + i * 16 + l15][kk + l4 * 8];
#pragma unroll
            for (int i = 0; i < 4; ++i)
                b[i] = *(const short8*)&Bs[wc * 64 + i * 16 + l15][kk + l4 * 8];
#pragma unroll
            for (int mi = 0; mi < 4; ++mi)
#pragma unroll
                for (int ni = 0; ni < 4; ++ni)
                    acc[mi][ni] = __builtin_amdgcn_mfma_f32_16x16x32_bf16(
                        a[mi], b[ni], acc[mi][ni], 0, 0, 0);
        }
    }
    // epilogue: C/D layout col=lane&15, row=(lane>>4)*4+reg
#pragma unroll
    for (int mi = 0; mi < 4; ++mi) {
        int mb = row0 + wr * 64 + mi * 16 + l4 * 4;
        float dv[4];
#pragma unroll
        for (int r = 0; r < 4; ++r) dv[r] = (mb + r < M) ? dinv[mb + r] : 0.f;
#pragma unroll
        for (int ni = 0; ni < 4; ++ni) {
            int n = col0 + wc * 64 + ni * 16 + l15;
#pragma unroll
            for (int r = 0; r < 4; ++r) {
                if (mb + r < M)
                    hwb[(size_t)(mb + r) * 256 + n] = f2b(acc[mi][ni][r] * dv[r]);
            }
        }
    }
}

// ---------------- CSR aggregation (bf16 gathers, 4x unrolled): one wave per node ----------------
__global__ void k_agg(const unsigned short* __restrict__ hwb, float* __restrict__ agg,
                      const int* __restrict__ csr, const int* __restrict__ rs,
                      const int* __restrict__ cnt, const float* __restrict__ dinv,
                      const float* __restrict__ bias, int N) {
    int wave = threadIdx.x >> 6;
    int lane = threadIdx.x & 63;
    int n = blockIdx.x * 4 + wave;
    if (n >= N) return;
    float dn = dinv[n];
    int e = rs[n];
    int end = e + cnt[n];
    // self term (hwb already carries dinv[src])
    float4 acc = bf4_to_f4(((const ushort4*)(hwb + (size_t)n * HH))[lane]);
    for (; e + 4 <= end; e += 4) {
        int s0 = csr[e], s1 = csr[e + 1], s2 = csr[e + 2], s3 = csr[e + 3];
        float4 m0 = bf4_to_f4(((const ushort4*)(hwb + (size_t)s0 * HH))[lane]);
        float4 m1 = bf4_to_f4(((const ushort4*)(hwb + (size_t)s1 * HH))[lane]);
        float4 m2 = bf4_to_f4(((const ushort4*)(hwb + (size_t)s2 * HH))[lane]);
        float4 m3 = bf4_to_f4(((const ushort4*)(hwb + (size_t)s3 * HH))[lane]);
        acc.x += (m0.x + m1.x) + (m2.x + m3.x);
        acc.y += (m0.y + m1.y) + (m2.y + m3.y);
        acc.z += (m0.z + m1.z) + (m2.z + m3.z);
        acc.w += (m0.w + m1.w) + (m2.w + m3.w);
    }
    for (; e < end; ++e) {
        int s = csr[e];
        float4 m = bf4_to_f4(((const ushort4*)(hwb + (size_t)s * HH))[lane]);
        acc.x += m.x; acc.y += m.y; acc.z += m.z; acc.w += m.w;
    }
    float4 b = ((const float4*)bias)[lane];
    float4 r;
    r.x = acc.x * dn + b.x; r.y = acc.y * dn + b.y;
    r.z = acc.z * dn + b.z; r.w = acc.w * dn + b.w;
    ((float4*)(agg + (size_t)n * HH))[lane] = r;
}

// ---------------- BN stats (col sum / sumsq) ----------------
__global__ void k_bnstats(const float4* __restrict__ agg, float* __restrict__ colsum,
                          float* __restrict__ colsq, int N) {
    int lane = threadIdx.x;  // 64
    int rows_per = (N + gridDim.x - 1) / gridDim.x;
    int r0 = blockIdx.x * rows_per;
    int r1 = r0 + rows_per; if (r1 > N) r1 = N;
    float4 s = make_float4(0.f, 0.f, 0.f, 0.f);
    float4 s2 = make_float4(0.f, 0.f, 0.f, 0.f);
    for (int r = r0; r < r1; ++r) {
        float4 v = agg[(size_t)r * 64 + lane];
        s.x += v.x; s.y += v.y; s.z += v.z; s.w += v.w;
        s2.x += v.x * v.x; s2.y += v.y * v.y; s2.z += v.z * v.z; s2.w += v.w * v.w;
    }
    int j = lane * 4;
    atomicAdd(&colsum[j + 0], s.x); atomicAdd(&colsum[j + 1], s.y);
    atomicAdd(&colsum[j + 2], s.z); atomicAdd(&colsum[j + 3], s.w);
    atomicAdd(&colsq[j + 0], s2.x); atomicAdd(&colsq[j + 1], s2.y);
    atomicAdd(&colsq[j + 2], s2.z); atomicAdd(&colsq[j + 3], s2.w);
}

// ---------------- BN + ReLU + residual (in-place into h, also refresh hb) ----------------
__global__ void k_epi(const float4* __restrict__ agg, float4* __restrict__ h,
                      ushort4* __restrict__ hb,
                      const float4* __restrict__ colsum, const float4* __restrict__ colsq,
                      const float4* __restrict__ g4, const float4* __restrict__ b4,
                      int total, float invN) {
    int idx = blockIdx.x * 256 + threadIdx.x;
    if (idx >= total) return;
    int q = idx & 63;
    float4 a = agg[idx];
    float4 s = colsum[q], s2 = colsq[q], g = g4[q], b = b4[q];
    float4 hv = h[idx];
    float mu, var, v;
    mu = s.x * invN; var = s2.x * invN - mu * mu;
    v = (a.x - mu) * rsqrtf(var + EPSF) * g.x + b.x; hv.x += fmaxf(v, 0.f);
    mu = s.y * invN; var = s2.y * invN - mu * mu;
    v = (a.y - mu) * rsqrtf(var + EPSF) * g.y + b.y; hv.y += fmaxf(v, 0.f);
    mu = s.z * invN; var = s2.z * invN - mu * mu;
    v = (a.z - mu) * rsqrtf(var + EPSF) * g.z + b.z; hv.z += fmaxf(v, 0.f);
    mu = s.w * invN; var = s2.w * invN - mu * mu;
    v = (a.w - mu) * rsqrtf(var + EPSF) * g.w + b.w; hv.w += fmaxf(v, 0.f);
    h[idx] = hv;
    ushort4 u;
    u.x = f2b(hv.x); u.y = f2b(hv.y); u.z = f2b(hv.z); u.w = f2b(hv.w);
    hb[idx] = u;
}

// ---------------- graph boundaries (batch is sorted) ----------------
__global__ void k_ginit(int* __restrict__ gstart, int G, int N) {
    int g = blockIdx.x * 256 + threadIdx.x;
    if (g <= G) gstart[g] = N;
}

__global__ void k_gbound(const int* __restrict__ batch, int* __restrict__ gstart, int N) {
    int n = blockIdx.x * 256 + threadIdx.x;
    if (n >= N) return;
    int b = batch[n];
    int prev = (n == 0) ? -1 : batch[n - 1];
    for (int g = prev + 1; g <= b; ++g) gstart[g] = n;
}

// ---------------- segmented mean pool: one block (4 waves) per graph ----------------
__global__ void k_pool(const float4* __restrict__ h, const int* __restrict__ gstart,
                       float* __restrict__ pooled) {
    __shared__ float4 sm[4][64];
    int g = blockIdx.x;
    int t = threadIdx.x;
    int lane = t & 63, wv = t >> 6;
    int s = gstart[g], e = gstart[g + 1];
    float4 acc = make_float4(0.f, 0.f, 0.f, 0.f);
    for (int n = s + wv; n < e; n += 4) {
        float4 v = h[(size_t)n * 64 + lane];
        acc.x += v.x; acc.y += v.y; acc.z += v.z; acc.w += v.w;
    }
    sm[wv][lane] = acc;
    __syncthreads();
    if (wv == 0) {
        float4 a = sm[0][lane], b = sm[1][lane], c = sm[2][lane], d = sm[3][lane];
        float inv = 1.0f / fmaxf((float)(e - s), 1.0f);
        float4 r;
        r.x = (a.x + b.x + c.x + d.x) * inv;
        r.y = (a.y + b.y + c.y + d.y) * inv;
        r.z = (a.z + b.z + c.z + d.z) * inv;
        r.w = (a.w + b.w + c.w + d.w) * inv;
        ((float4*)pooled)[(size_t)g * 64 + lane] = r;
    }
}

// ---------------- MLP head: one block per graph ----------------
__global__ void k_head(const float* __restrict__ pooled,
                       const float* __restrict__ W1, const float* __restrict__ b1,
                       const float* __restrict__ W2, const float* __restrict__ b2,
                       float* __restrict__ out) {
    __shared__ float prow[256];
    __shared__ float hred[128];
    int g = blockIdx.x, t = threadIdx.x;  // 128 threads
    prow[t] = pooled[(size_t)g * HH + t];
    prow[t + 128] = pooled[(size_t)g * HH + t + 128];
    __syncthreads();
    float acc = b1[t];
    for (int k = 0; k < HH; ++k) acc += prow[k] * W1[(size_t)k * 128 + t];
    float hid = fmaxf(acc, 0.f);
    hred[t] = hid * W2[t];
    __syncthreads();
    for (int off = 64; off > 0; off >>= 1) {
        if (t < off) hred[t] += hred[t + off];
        __syncthreads();
    }
    if (t == 0) out[g] = hred[0] + b2[0];
}

extern "C" void kernel_launch(void* const* d_in, const int* in_sizes, int n_in,
                              void* d_out, int out_size, void* d_ws, size_t ws_size,
                              hipStream_t stream) {
    const int* x        = (const int*)d_in[0];
    const int* tags     = (const int*)d_in[1];
    const int* ei       = (const int*)d_in[2];
    const int* batch    = (const int*)d_in[3];
    const float* atom_e = (const float*)d_in[4];
    const float* tag_e  = (const float*)d_in[5];
    const float* Wp     = (const float*)d_in[6];
    const float* bp     = (const float*)d_in[7];
    const float* gcn_W  = (const float*)d_in[8];
    const float* gcn_b  = (const float*)d_in[9];
    const float* bn_g   = (const float*)d_in[10];
    const float* bn_b   = (const float*)d_in[11];
    const float* W1     = (const float*)d_in[12];
    const float* b1     = (const float*)d_in[13];
    const float* W2     = (const float*)d_in[14];
    const float* b2     = (const float*)d_in[15];
    float* out = (float*)d_out;

    const int N = NN, E = EE, G = GG, H = HH;
    const int Mpad = ((N + 127) / 128) * 128;  // 50048

    char* p = (char*)d_ws;
    auto alloc = [&](size_t bytes) {
        void* r = (void*)p;
        p += (bytes + 255) & ~(size_t)255;
        return r;
    };
    float* h    = (float*)alloc((size_t)N * H * 4);
    unsigned short* hb  = (unsigned short*)alloc((size_t)Mpad * H * 2);
    unsigned short* hwb = (unsigned short*)alloc((size_t)Mpad * H * 2);
    unsigned short* Wt  = (unsigned short*)alloc((size_t)LL * H * H * 2);
    float* agg  = (float*)alloc((size_t)N * H * 4);
    float* dinv = (float*)alloc((size_t)N * 4);
    int* cnt    = (int*)alloc((size_t)N * 4);
    int* rs     = (int*)alloc((size_t)N * 4);
    int* cur    = (int*)alloc((size_t)N * 4);
    int* csr    = (int*)alloc((size_t)E * 4);
    int* bsum   = (int*)alloc(64 * 4);
    float* aref = (float*)alloc(100 * (size_t)H * 4);
    float* tref = (float*)alloc(3 * (size_t)H * 4);
    float* cstat= (float*)alloc(2 * (size_t)H * 4);  // colsum | colsq
    int* gstart = (int*)alloc((size_t)(G + 1) * 4);
    float* pooled = (float*)alloc((size_t)G * H * 4);

    const int* src = ei;
    const int* dst = ei + E;

    hipMemsetAsync(cnt, 0, (size_t)N * 4, stream);
    hipMemsetAsync(cur, 0, (size_t)N * 4, stream);

    k_degree<<<(E + 255) / 256, 256, 0, stream>>>(dst, cnt, E);
    k_dinv<<<(N + 255) / 256, 256, 0, stream>>>(cnt, dinv, N);

    int nb = (N + 1023) / 1024;
    k_scan1<<<nb, 1024, 0, stream>>>(cnt, rs, bsum, N);
    k_scan2<<<1, 64, 0, stream>>>(bsum, nb);
    k_scan3<<<(N + 255) / 256, 256, 0, stream>>>(rs, cnt, bsum, N);
    k_scatter<<<(E + 255) / 256, 256, 0, stream>>>(src, dst, rs, cur, csr, E);

    k_ginit<<<(G + 256) / 256, 256, 0, stream>>>(gstart, G, N);
    k_gbound<<<(N + 255) / 256, 256, 0, stream>>>(batch, gstart, N);

    k_wprep<<<dim3(64, LL), 256, 0, stream>>>(gcn_W, Wt);
    k_proj<<<103, 256, 0, stream>>>(atom_e, tag_e, Wp, bp, aref, tref);
    k_h0<<<N, 64, 0, stream>>>(x, tags, aref, tref, h, hb, N);

    for (int l = 0; l < LL; ++l) {
        k_gemm<<<dim3(2, Mpad / 128), 256, 0, stream>>>(
            hb, Wt + (size_t)l * H * H, dinv, hwb, N);
        k_agg<<<(N + 3) / 4, 256, 0, stream>>>(hwb, agg, csr, rs, cnt, dinv,
                                               gcn_b + (size_t)l * H, N);
        hipMemsetAsync(cstat, 0, 2 * (size_t)H * 4, stream);
        k_bnstats<<<512, 64, 0, stream>>>((const float4*)agg, cstat, cstat + H, N);
        k_epi<<<(N * 64 + 255) / 256, 256, 0, stream>>>(
            (const float4*)agg, (float4*)h, (ushort4*)hb,
            (const float4*)cstat, (const float4*)(cstat + H),
            (const float4*)(bn_g + (size_t)l * H), (const float4*)(bn_b + (size_t)l * H),
            N * 64, 1.0f / (float)N);
    }

    k_pool<<<G, 256, 0, stream>>>((const float4*)h, gstart, pooled);
    k_head<<<G, 128, 0, stream>>>(pooled, W1, b1, W2, b2, out);
}

// Round 4
// 941.797 us; speedup vs baseline: 2.0300x; 1.0581x over previous
//
#include <hip/hip_runtime.h>
#include <hip/hip_bf16.h>

#define NN 50000
#define EE 800000
#define GG 512
#define HH 256
#define TT 32
#define LL 4
#define EPSF 1e-5f

typedef __attribute__((ext_vector_type(8))) short short8;
typedef __attribute__((ext_vector_type(4))) float float4v;

// ---------- bf16 helpers ----------
__device__ inline unsigned short f2b(float f) {  // RNE
    unsigned u = __float_as_uint(f);
    unsigned r = (u + 0x7FFFu + ((u >> 16) & 1u)) >> 16;
    return (unsigned short)r;
}
__device__ inline float4 bf4_to_f4(ushort4 u) {
    float4 f;
    f.x = __uint_as_float((unsigned)u.x << 16);
    f.y = __uint_as_float((unsigned)u.y << 16);
    f.z = __uint_as_float((unsigned)u.z << 16);
    f.w = __uint_as_float((unsigned)u.w << 16);
    return f;
}

// ---------------- degree / dinv ----------------
__global__ void k_degree(const int* __restrict__ dst, int* __restrict__ cnt, int E) {
    int e = blockIdx.x * 256 + threadIdx.x;
    if (e < E) atomicAdd(&cnt[dst[e]], 1);
}

__global__ void k_dinv(const int* __restrict__ cnt, float* __restrict__ dinv, int N) {
    int i = blockIdx.x * 256 + threadIdx.x;
    if (i < N) dinv[i] = rsqrtf((float)cnt[i] + 1.0f);
}

// ---------------- scan (3-phase, 1024/block) ----------------
__global__ void k_scan1(const int* __restrict__ cnt, int* __restrict__ incl,
                        int* __restrict__ bsum, int N) {
    __shared__ int s[1024];
    int i = blockIdx.x * 1024 + threadIdx.x;
    int v = (i < N) ? cnt[i] : 0;
    s[threadIdx.x] = v;
    __syncthreads();
    for (int off = 1; off < 1024; off <<= 1) {
        int t = (threadIdx.x >= off) ? s[threadIdx.x - off] : 0;
        __syncthreads();
        s[threadIdx.x] += t;
        __syncthreads();
    }
    if (i < N) incl[i] = s[threadIdx.x];
    if (threadIdx.x == 1023) bsum[blockIdx.x] = s[1023];
}

__global__ void k_scan2(int* __restrict__ bsum, int nb) {
    __shared__ int s[64];
    int v = (threadIdx.x < nb) ? bsum[threadIdx.x] : 0;
    s[threadIdx.x] = v;
    __syncthreads();
    for (int off = 1; off < 64; off <<= 1) {
        int t = (threadIdx.x >= off) ? s[threadIdx.x - off] : 0;
        __syncthreads();
        s[threadIdx.x] += t;
        __syncthreads();
    }
    if (threadIdx.x < nb) bsum[threadIdx.x] = s[threadIdx.x] - v;  // exclusive
}

__global__ void k_scan3(int* __restrict__ rs, const int* __restrict__ cnt,
                        const int* __restrict__ boff, int N) {
    int i = blockIdx.x * 256 + threadIdx.x;
    if (i < N) rs[i] = rs[i] + boff[i >> 10] - cnt[i];  // exclusive prefix
}

__global__ void k_scatter(const int* __restrict__ src, const int* __restrict__ dst,
                          const int* __restrict__ rs, int* __restrict__ cur,
                          int* __restrict__ csr, int E) {
    int e = blockIdx.x * 256 + threadIdx.x;
    if (e >= E) return;
    int d = dst[e];
    int p = rs[d] + atomicAdd(&cur[d], 1);
    csr[p] = src[e];
}

// ---------------- weight prep: Wt[l][n][k] bf16 ----------------
__global__ void k_wprep(const float* __restrict__ W, unsigned short* __restrict__ Wt) {
    int l = blockIdx.y;
    int n = blockIdx.x * 4 + (threadIdx.x >> 6);
    int kq = (threadIdx.x & 63) * 4;
    const float* Wl = W + (size_t)l * HH * HH;
    ushort4 o;
    o.x = f2b(Wl[(size_t)(kq + 0) * HH + n]);
    o.y = f2b(Wl[(size_t)(kq + 1) * HH + n]);
    o.z = f2b(Wl[(size_t)(kq + 2) * HH + n]);
    o.w = f2b(Wl[(size_t)(kq + 3) * HH + n]);
    *(ushort4*)(Wt + (size_t)l * HH * HH + (size_t)n * HH + kq) = o;
}

// ---------------- tiny projection: atom_proj (100x256) + tag_proj (3x256) ----------------
__global__ void k_proj(const float* __restrict__ atom_emb, const float* __restrict__ tag_emb,
                       const float* __restrict__ Wp, const float* __restrict__ bp,
                       float* __restrict__ aref, float* __restrict__ tref) {
    int r = blockIdx.x;
    int j = threadIdx.x;  // 256
    if (r < 100) {
        float acc = bp[j];
        for (int k = 0; k < HH; ++k) acc += atom_emb[r * HH + k] * Wp[(size_t)k * HH + j];
        aref[r * HH + j] = acc;
    } else {
        int tr = r - 100;
        float acc = 0.f;
        for (int k = 0; k < TT; ++k) acc += tag_emb[tr * TT + k] * Wp[(size_t)(HH + k) * HH + j];
        tref[tr * HH + j] = acc;
    }
}

__global__ void k_h0(const int* __restrict__ x, const int* __restrict__ tags,
                     const float* __restrict__ aref, const float* __restrict__ tref,
                     float* __restrict__ h, unsigned short* __restrict__ hb, int N) {
    int n = blockIdx.x;
    int lane = threadIdx.x;  // 64
    float4 a = ((const float4*)(aref + (size_t)x[n] * HH))[lane];
    float4 t = ((const float4*)(tref + (size_t)tags[n] * HH))[lane];
    float4 r;
    r.x = a.x + t.x; r.y = a.y + t.y; r.z = a.z + t.z; r.w = a.w + t.w;
    ((float4*)(h + (size_t)n * HH))[lane] = r;
    ushort4 u;
    u.x = f2b(r.x); u.y = f2b(r.y); u.z = f2b(r.z); u.w = f2b(r.w);
    ((ushort4*)(hb + (size_t)n * HH))[lane] = u;
}

// ---------------- MFMA bf16 GEMM: hwb[M,256] = bf16( (hb @ Wt^T) * dinv[row] ) ----------------
__global__ __launch_bounds__(256) void k_gemm(const unsigned short* __restrict__ hb,
                                              const unsigned short* __restrict__ Wt,
                                              const float* __restrict__ dinv,
                                              unsigned short* __restrict__ hwb, int M) {
    __shared__ unsigned short As[128][72];
    __shared__ unsigned short Bs[128][72];
    int t = threadIdx.x;
    int lane = t & 63, w = t >> 6;
    int wr = w >> 1, wc = w & 1;
    int l15 = lane & 15, l4 = lane >> 4;
    int row0 = blockIdx.y * 128, col0 = blockIdx.x * 128;
    float4v acc[4][4];
#pragma unroll
    for (int i = 0; i < 4; ++i)
#pragma unroll
        for (int j = 0; j < 4; ++j) acc[i][j] = (float4v)0.f;

    for (int k0 = 0; k0 < 256; k0 += 64) {
        if (k0) __syncthreads();
#pragma unroll
        for (int u = 0; u < 4; ++u) {
            int idx = u * 256 + t;          // 0..1023
            int r = idx >> 3;               // 0..127
            int c = (idx & 7) * 8;          // bf16 col
            *(uint4*)&As[r][c] = *(const uint4*)(hb + (size_t)(row0 + r) * 256 + k0 + c);
            *(uint4*)&Bs[r][c] = *(const uint4*)(Wt + (size_t)(col0 + r) * 256 + k0 + c);
        }
        __syncthreads();
#pragma unroll
        for (int kk = 0; kk < 64; kk += 32) {
            short8 a[4], b[4];
#pragma unroll
            for (int i = 0; i < 4; ++i)
                a[i] = *(const short8*)&As[wr * 64 + i * 16 + l15][kk + l4 * 8];
#pragma unroll
            for (int i = 0; i < 4; ++i)
                b[i] = *(const short8*)&Bs[wc * 64 + i * 16 + l15][kk + l4 * 8];
#pragma unroll
            for (int mi = 0; mi < 4; ++mi)
#pragma unroll
                for (int ni = 0; ni < 4; ++ni)
                    acc[mi][ni] = __builtin_amdgcn_mfma_f32_16x16x32_bf16(
                        a[mi], b[ni], acc[mi][ni], 0, 0, 0);
        }
    }
    // epilogue: C/D layout col=lane&15, row=(lane>>4)*4+reg
#pragma unroll
    for (int mi = 0; mi < 4; ++mi) {
        int mb = row0 + wr * 64 + mi * 16 + l4 * 4;
        float dv[4];
#pragma unroll
        for (int r = 0; r < 4; ++r) dv[r] = (mb + r < M) ? dinv[mb + r] : 0.f;
#pragma unroll
        for (int ni = 0; ni < 4; ++ni) {
            int n = col0 + wc * 64 + ni * 16 + l15;
#pragma unroll
            for (int r = 0; r < 4; ++r) {
                if (mb + r < M)
                    hwb[(size_t)(mb + r) * 256 + n] = f2b(acc[mi][ni][r] * dv[r]);
            }
        }
    }
}

// ---------------- CSR aggregation (bf16 gathers, 4x unrolled): one wave per node ----------------
__global__ void k_agg(const unsigned short* __restrict__ hwb, float* __restrict__ agg,
                      const int* __restrict__ csr, const int* __restrict__ rs,
                      const int* __restrict__ cnt, const float* __restrict__ dinv,
                      const float* __restrict__ bias, int N) {
    int wave = threadIdx.x >> 6;
    int lane = threadIdx.x & 63;
    int n = blockIdx.x * 4 + wave;
    if (n >= N) return;
    float dn = dinv[n];
    int e = rs[n];
    int end = e + cnt[n];
    // self term (hwb already carries dinv[src])
    float4 acc = bf4_to_f4(((const ushort4*)(hwb + (size_t)n * HH))[lane]);
    for (; e + 4 <= end; e += 4) {
        int s0 = csr[e], s1 = csr[e + 1], s2 = csr[e + 2], s3 = csr[e + 3];
        float4 m0 = bf4_to_f4(((const ushort4*)(hwb + (size_t)s0 * HH))[lane]);
        float4 m1 = bf4_to_f4(((const ushort4*)(hwb + (size_t)s1 * HH))[lane]);
        float4 m2 = bf4_to_f4(((const ushort4*)(hwb + (size_t)s2 * HH))[lane]);
        float4 m3 = bf4_to_f4(((const ushort4*)(hwb + (size_t)s3 * HH))[lane]);
        acc.x += (m0.x + m1.x) + (m2.x + m3.x);
        acc.y += (m0.y + m1.y) + (m2.y + m3.y);
        acc.z += (m0.z + m1.z) + (m2.z + m3.z);
        acc.w += (m0.w + m1.w) + (m2.w + m3.w);
    }
    for (; e < end; ++e) {
        int s = csr[e];
        float4 m = bf4_to_f4(((const ushort4*)(hwb + (size_t)s * HH))[lane]);
        acc.x += m.x; acc.y += m.y; acc.z += m.z; acc.w += m.w;
    }
    float4 b = ((const float4*)bias)[lane];
    float4 r;
    r.x = acc.x * dn + b.x; r.y = acc.y * dn + b.y;
    r.z = acc.z * dn + b.z; r.w = acc.w * dn + b.w;
    ((float4*)(agg + (size_t)n * HH))[lane] = r;
}

// ---------------- BN stats (col sum / sumsq), high-occupancy version ----------------
// 256 threads (4 waves), each wave strides rows; LDS cross-wave reduce; block atomics.
__global__ __launch_bounds__(256) void k_bnstats(const float4* __restrict__ agg,
                                                 float* __restrict__ colsum,
                                                 float* __restrict__ colsq, int N) {
    __shared__ float4 ssum[4][64];
    __shared__ float4 ssq[4][64];
    int lane = threadIdx.x & 63;
    int wv = threadIdx.x >> 6;
    int rows_per = (N + gridDim.x - 1) / gridDim.x;
    int r0 = blockIdx.x * rows_per;
    int r1 = r0 + rows_per; if (r1 > N) r1 = N;
    float4 s = make_float4(0.f, 0.f, 0.f, 0.f);
    float4 s2 = make_float4(0.f, 0.f, 0.f, 0.f);
    for (int r = r0 + wv; r < r1; r += 4) {
        float4 v = agg[(size_t)r * 64 + lane];
        s.x += v.x; s.y += v.y; s.z += v.z; s.w += v.w;
        s2.x += v.x * v.x; s2.y += v.y * v.y; s2.z += v.z * v.z; s2.w += v.w * v.w;
    }
    ssum[wv][lane] = s;
    ssq[wv][lane] = s2;
    __syncthreads();
    int j = lane * 4;
    if (wv == 0) {
        float4 a = ssum[0][lane], b = ssum[1][lane], c = ssum[2][lane], d = ssum[3][lane];
        atomicAdd(&colsum[j + 0], a.x + b.x + c.x + d.x);
        atomicAdd(&colsum[j + 1], a.y + b.y + c.y + d.y);
        atomicAdd(&colsum[j + 2], a.z + b.z + c.z + d.z);
        atomicAdd(&colsum[j + 3], a.w + b.w + c.w + d.w);
    } else if (wv == 1) {
        float4 a = ssq[0][lane], b = ssq[1][lane], c = ssq[2][lane], d = ssq[3][lane];
        atomicAdd(&colsq[j + 0], a.x + b.x + c.x + d.x);
        atomicAdd(&colsq[j + 1], a.y + b.y + c.y + d.y);
        atomicAdd(&colsq[j + 2], a.z + b.z + c.z + d.z);
        atomicAdd(&colsq[j + 3], a.w + b.w + c.w + d.w);
    }
}

// ---------------- BN + ReLU + residual (in-place into h, also refresh hb) ----------------
__global__ void k_epi(const float4* __restrict__ agg, float4* __restrict__ h,
                      ushort4* __restrict__ hb,
                      const float4* __restrict__ colsum, const float4* __restrict__ colsq,
                      const float4* __restrict__ g4, const float4* __restrict__ b4,
                      int total, float invN) {
    int idx = blockIdx.x * 256 + threadIdx.x;
    if (idx >= total) return;
    int q = idx & 63;
    float4 a = agg[idx];
    float4 s = colsum[q], s2 = colsq[q], g = g4[q], b = b4[q];
    float4 hv = h[idx];
    float mu, var, v;
    mu = s.x * invN; var = s2.x * invN - mu * mu;
    v = (a.x - mu) * rsqrtf(var + EPSF) * g.x + b.x; hv.x += fmaxf(v, 0.f);
    mu = s.y * invN; var = s2.y * invN - mu * mu;
    v = (a.y - mu) * rsqrtf(var + EPSF) * g.y + b.y; hv.y += fmaxf(v, 0.f);
    mu = s.z * invN; var = s2.z * invN - mu * mu;
    v = (a.z - mu) * rsqrtf(var + EPSF) * g.z + b.z; hv.z += fmaxf(v, 0.f);
    mu = s.w * invN; var = s2.w * invN - mu * mu;
    v = (a.w - mu) * rsqrtf(var + EPSF) * g.w + b.w; hv.w += fmaxf(v, 0.f);
    h[idx] = hv;
    ushort4 u;
    u.x = f2b(hv.x); u.y = f2b(hv.y); u.z = f2b(hv.z); u.w = f2b(hv.w);
    hb[idx] = u;
}

// ---------------- graph boundaries (batch is sorted) ----------------
__global__ void k_ginit(int* __restrict__ gstart, int G, int N) {
    int g = blockIdx.x * 256 + threadIdx.x;
    if (g <= G) gstart[g] = N;
}

__global__ void k_gbound(const int* __restrict__ batch, int* __restrict__ gstart, int N) {
    int n = blockIdx.x * 256 + threadIdx.x;
    if (n >= N) return;
    int b = batch[n];
    int prev = (n == 0) ? -1 : batch[n - 1];
    for (int g = prev + 1; g <= b; ++g) gstart[g] = n;
}

// ---------------- segmented mean pool: one block (4 waves) per graph ----------------
__global__ void k_pool(const float4* __restrict__ h, const int* __restrict__ gstart,
                       float* __restrict__ pooled) {
    __shared__ float4 sm[4][64];
    int g = blockIdx.x;
    int t = threadIdx.x;
    int lane = t & 63, wv = t >> 6;
    int s = gstart[g], e = gstart[g + 1];
    float4 acc = make_float4(0.f, 0.f, 0.f, 0.f);
    for (int n = s + wv; n < e; n += 4) {
        float4 v = h[(size_t)n * 64 + lane];
        acc.x += v.x; acc.y += v.y; acc.z += v.z; acc.w += v.w;
    }
    sm[wv][lane] = acc;
    __syncthreads();
    if (wv == 0) {
        float4 a = sm[0][lane], b = sm[1][lane], c = sm[2][lane], d = sm[3][lane];
        float inv = 1.0f / fmaxf((float)(e - s), 1.0f);
        float4 r;
        r.x = (a.x + b.x + c.x + d.x) * inv;
        r.y = (a.y + b.y + c.y + d.y) * inv;
        r.z = (a.z + b.z + c.z + d.z) * inv;
        r.w = (a.w + b.w + c.w + d.w) * inv;
        ((float4*)pooled)[(size_t)g * 64 + lane] = r;
    }
}

// ---------------- MLP head: one block per graph ----------------
__global__ void k_head(const float* __restrict__ pooled,
                       const float* __restrict__ W1, const float* __restrict__ b1,
                       const float* __restrict__ W2, const float* __restrict__ b2,
                       float* __restrict__ out) {
    __shared__ float prow[256];
    __shared__ float hred[128];
    int g = blockIdx.x, t = threadIdx.x;  // 128 threads
    prow[t] = pooled[(size_t)g * HH + t];
    prow[t + 128] = pooled[(size_t)g * HH + t + 128];
    __syncthreads();
    float acc = b1[t];
    for (int k = 0; k < HH; ++k) acc += prow[k] * W1[(size_t)k * 128 + t];
    float hid = fmaxf(acc, 0.f);
    hred[t] = hid * W2[t];
    __syncthreads();
    for (int off = 64; off > 0; off >>= 1) {
        if (t < off) hred[t] += hred[t + off];
        __syncthreads();
    }
    if (t == 0) out[g] = hred[0] + b2[0];
}

extern "C" void kernel_launch(void* const* d_in, const int* in_sizes, int n_in,
                              void* d_out, int out_size, void* d_ws, size_t ws_size,
                              hipStream_t stream) {
    const int* x        = (const int*)d_in[0];
    const int* tags     = (const int*)d_in[1];
    const int* ei       = (const int*)d_in[2];
    const int* batch    = (const int*)d_in[3];
    const float* atom_e = (const float*)d_in[4];
    const float* tag_e  = (const float*)d_in[5];
    const float* Wp     = (const float*)d_in[6];
    const float* bp     = (const float*)d_in[7];
    const float* gcn_W  = (const float*)d_in[8];
    const float* gcn_b  = (const float*)d_in[9];
    const float* bn_g   = (const float*)d_in[10];
    const float* bn_b   = (const float*)d_in[11];
    const float* W1     = (const float*)d_in[12];
    const float* b1     = (const float*)d_in[13];
    const float* W2     = (const float*)d_in[14];
    const float* b2     = (const float*)d_in[15];
    float* out = (float*)d_out;

    const int N = NN, E = EE, G = GG, H = HH;
    const int Mpad = ((N + 127) / 128) * 128;  // 50048

    char* p = (char*)d_ws;
    auto alloc = [&](size_t bytes) {
        void* r = (void*)p;
        p += (bytes + 255) & ~(size_t)255;
        return r;
    };
    float* h    = (float*)alloc((size_t)N * H * 4);
    unsigned short* hb  = (unsigned short*)alloc((size_t)Mpad * H * 2);
    unsigned short* hwb = (unsigned short*)alloc((size_t)Mpad * H * 2);
    unsigned short* Wt  = (unsigned short*)alloc((size_t)LL * H * H * 2);
    float* agg  = (float*)alloc((size_t)N * H * 4);
    float* dinv = (float*)alloc((size_t)N * 4);
    int* cnt    = (int*)alloc((size_t)N * 4);
    int* rs     = (int*)alloc((size_t)N * 4);
    int* cur    = (int*)alloc((size_t)N * 4);
    int* csr    = (int*)alloc((size_t)E * 4);
    int* bsum   = (int*)alloc(64 * 4);
    float* aref = (float*)alloc(100 * (size_t)H * 4);
    float* tref = (float*)alloc(3 * (size_t)H * 4);
    float* cstat= (float*)alloc(2 * (size_t)H * 4);  // colsum | colsq
    int* gstart = (int*)alloc((size_t)(G + 1) * 4);
    float* pooled = (float*)alloc((size_t)G * H * 4);

    const int* src = ei;
    const int* dst = ei + E;

    hipMemsetAsync(cnt, 0, (size_t)N * 4, stream);
    hipMemsetAsync(cur, 0, (size_t)N * 4, stream);

    k_degree<<<(E + 255) / 256, 256, 0, stream>>>(dst, cnt, E);
    k_dinv<<<(N + 255) / 256, 256, 0, stream>>>(cnt, dinv, N);

    int nb = (N + 1023) / 1024;
    k_scan1<<<nb, 1024, 0, stream>>>(cnt, rs, bsum, N);
    k_scan2<<<1, 64, 0, stream>>>(bsum, nb);
    k_scan3<<<(N + 255) / 256, 256, 0, stream>>>(rs, cnt, bsum, N);
    k_scatter<<<(E + 255) / 256, 256, 0, stream>>>(src, dst, rs, cur, csr, E);

    k_ginit<<<(G + 256) / 256, 256, 0, stream>>>(gstart, G, N);
    k_gbound<<<(N + 255) / 256, 256, 0, stream>>>(batch, gstart, N);

    k_wprep<<<dim3(64, LL), 256, 0, stream>>>(gcn_W, Wt);
    k_proj<<<103, 256, 0, stream>>>(atom_e, tag_e, Wp, bp, aref, tref);
    k_h0<<<N, 64, 0, stream>>>(x, tags, aref, tref, h, hb, N);

    for (int l = 0; l < LL; ++l) {
        k_gemm<<<dim3(2, Mpad / 128), 256, 0, stream>>>(
            hb, Wt + (size_t)l * H * H, dinv, hwb, N);
        k_agg<<<(N + 3) / 4, 256, 0, stream>>>(hwb, agg, csr, rs, cnt, dinv,
                                               gcn_b + (size_t)l * H, N);
        hipMemsetAsync(cstat, 0, 2 * (size_t)H * 4, stream);
        k_bnstats<<<512, 256, 0, stream>>>((const float4*)agg, cstat, cstat + H, N);
        k_epi<<<(N * 64 + 255) / 256, 256, 0, stream>>>(
            (const float4*)agg, (float4*)h, (ushort4*)hb,
            (const float4*)cstat, (const float4*)(cstat + H),
            (const float4*)(bn_g + (size_t)l * H), (const float4*)(bn_b + (size_t)l * H),
            N * 64, 1.0f / (float)N);
    }

    k_pool<<<G, 256, 0, stream>>>((const float4*)h, gstart, pooled);
    k_head<<<G, 128, 0, stream>>>(pooled, W1, b1, W2, b2, out);
}

// Round 5
// 899.928 us; speedup vs baseline: 2.1244x; 1.0465x over previous
//
#include <hip/hip_runtime.h>
#include <hip/hip_bf16.h>

#define NN 50000
#define EE 800000
#define GG 512
#define HH 256
#define TT 32
#define LL 4
#define EPSF 1e-5f

typedef __attribute__((ext_vector_type(8))) short short8;
typedef __attribute__((ext_vector_type(4))) float float4v;

// ---------- bf16 helpers ----------
__device__ inline unsigned short f2b(float f) {  // RNE
    unsigned u = __float_as_uint(f);
    unsigned r = (u + 0x7FFFu + ((u >> 16) & 1u)) >> 16;
    return (unsigned short)r;
}
__device__ inline float4 bf4_to_f4(ushort4 u) {
    float4 f;
    f.x = __uint_as_float((unsigned)u.x << 16);
    f.y = __uint_as_float((unsigned)u.y << 16);
    f.z = __uint_as_float((unsigned)u.z << 16);
    f.w = __uint_as_float((unsigned)u.w << 16);
    return f;
}

// ---------------- degree / dinv ----------------
__global__ void k_degree(const int* __restrict__ dst, int* __restrict__ cnt, int E) {
    int e = blockIdx.x * 256 + threadIdx.x;
    if (e < E) atomicAdd(&cnt[dst[e]], 1);
}

__global__ void k_dinv(const int* __restrict__ cnt, float* __restrict__ dinv, int N) {
    int i = blockIdx.x * 256 + threadIdx.x;
    if (i < N) dinv[i] = rsqrtf((float)cnt[i] + 1.0f);
}

// ---------------- scan (3-phase, 1024/block) ----------------
__global__ void k_scan1(const int* __restrict__ cnt, int* __restrict__ incl,
                        int* __restrict__ bsum, int N) {
    __shared__ int s[1024];
    int i = blockIdx.x * 1024 + threadIdx.x;
    int v = (i < N) ? cnt[i] : 0;
    s[threadIdx.x] = v;
    __syncthreads();
    for (int off = 1; off < 1024; off <<= 1) {
        int t = (threadIdx.x >= off) ? s[threadIdx.x - off] : 0;
        __syncthreads();
        s[threadIdx.x] += t;
        __syncthreads();
    }
    if (i < N) incl[i] = s[threadIdx.x];
    if (threadIdx.x == 1023) bsum[blockIdx.x] = s[1023];
}

__global__ void k_scan2(int* __restrict__ bsum, int nb) {
    __shared__ int s[64];
    int v = (threadIdx.x < nb) ? bsum[threadIdx.x] : 0;
    s[threadIdx.x] = v;
    __syncthreads();
    for (int off = 1; off < 64; off <<= 1) {
        int t = (threadIdx.x >= off) ? s[threadIdx.x - off] : 0;
        __syncthreads();
        s[threadIdx.x] += t;
        __syncthreads();
    }
    if (threadIdx.x < nb) bsum[threadIdx.x] = s[threadIdx.x] - v;  // exclusive
}

__global__ void k_scan3(int* __restrict__ rs, const int* __restrict__ cnt,
                        const int* __restrict__ boff, int N) {
    int i = blockIdx.x * 256 + threadIdx.x;
    if (i < N) rs[i] = rs[i] + boff[i >> 10] - cnt[i];  // exclusive prefix
}

__global__ void k_scatter(const int* __restrict__ src, const int* __restrict__ dst,
                          const int* __restrict__ rs, int* __restrict__ cur,
                          int* __restrict__ csr, int E) {
    int e = blockIdx.x * 256 + threadIdx.x;
    if (e >= E) return;
    int d = dst[e];
    int p = rs[d] + atomicAdd(&cur[d], 1);
    csr[p] = src[e];
}

// ---------------- weight prep: Wt[l][n][k] bf16 ----------------
__global__ void k_wprep(const float* __restrict__ W, unsigned short* __restrict__ Wt) {
    int l = blockIdx.y;
    int n = blockIdx.x * 4 + (threadIdx.x >> 6);
    int kq = (threadIdx.x & 63) * 4;
    const float* Wl = W + (size_t)l * HH * HH;
    ushort4 o;
    o.x = f2b(Wl[(size_t)(kq + 0) * HH + n]);
    o.y = f2b(Wl[(size_t)(kq + 1) * HH + n]);
    o.z = f2b(Wl[(size_t)(kq + 2) * HH + n]);
    o.w = f2b(Wl[(size_t)(kq + 3) * HH + n]);
    *(ushort4*)(Wt + (size_t)l * HH * HH + (size_t)n * HH + kq) = o;
}

// ---------------- tiny projection: atom_proj (100x256) + tag_proj (3x256) ----------------
__global__ void k_proj(const float* __restrict__ atom_emb, const float* __restrict__ tag_emb,
                       const float* __restrict__ Wp, const float* __restrict__ bp,
                       float* __restrict__ aref, float* __restrict__ tref) {
    int r = blockIdx.x;
    int j = threadIdx.x;  // 256
    if (r < 100) {
        float acc = bp[j];
        for (int k = 0; k < HH; ++k) acc += atom_emb[r * HH + k] * Wp[(size_t)k * HH + j];
        aref[r * HH + j] = acc;
    } else {
        int tr = r - 100;
        float acc = 0.f;
        for (int k = 0; k < TT; ++k) acc += tag_emb[tr * TT + k] * Wp[(size_t)(HH + k) * HH + j];
        tref[tr * HH + j] = acc;
    }
}

__global__ void k_h0(const int* __restrict__ x, const int* __restrict__ tags,
                     const float* __restrict__ aref, const float* __restrict__ tref,
                     unsigned short* __restrict__ hb, int N) {
    int n = blockIdx.x;
    int lane = threadIdx.x;  // 64
    float4 a = ((const float4*)(aref + (size_t)x[n] * HH))[lane];
    float4 t = ((const float4*)(tref + (size_t)tags[n] * HH))[lane];
    ushort4 u;
    u.x = f2b(a.x + t.x); u.y = f2b(a.y + t.y);
    u.z = f2b(a.z + t.z); u.w = f2b(a.w + t.w);
    ((ushort4*)(hb + (size_t)n * HH))[lane] = u;
}

// ---------------- MFMA bf16 GEMM: hwb[M,256] = bf16( (hb @ Wt^T) * dinv[row] ) ----------------
__global__ __launch_bounds__(256) void k_gemm(const unsigned short* __restrict__ hb,
                                              const unsigned short* __restrict__ Wt,
                                              const float* __restrict__ dinv,
                                              unsigned short* __restrict__ hwb, int M) {
    __shared__ unsigned short As[128][72];
    __shared__ unsigned short Bs[128][72];
    int t = threadIdx.x;
    int lane = t & 63, w = t >> 6;
    int wr = w >> 1, wc = w & 1;
    int l15 = lane & 15, l4 = lane >> 4;
    int row0 = blockIdx.y * 128, col0 = blockIdx.x * 128;
    float4v acc[4][4];
#pragma unroll
    for (int i = 0; i < 4; ++i)
#pragma unroll
        for (int j = 0; j < 4; ++j) acc[i][j] = (float4v)0.f;

    for (int k0 = 0; k0 < 256; k0 += 64) {
        if (k0) __syncthreads();
#pragma unroll
        for (int u = 0; u < 4; ++u) {
            int idx = u * 256 + t;          // 0..1023
            int r = idx >> 3;               // 0..127
            int c = (idx & 7) * 8;          // bf16 col
            *(uint4*)&As[r][c] = *(const uint4*)(hb + (size_t)(row0 + r) * 256 + k0 + c);
            *(uint4*)&Bs[r][c] = *(const uint4*)(Wt + (size_t)(col0 + r) * 256 + k0 + c);
        }
        __syncthreads();
#pragma unroll
        for (int kk = 0; kk < 64; kk += 32) {
            short8 a[4], b[4];
#pragma unroll
            for (int i = 0; i < 4; ++i)
                a[i] = *(const short8*)&As[wr * 64 + i * 16 + l15][kk + l4 * 8];
#pragma unroll
            for (int i = 0; i < 4; ++i)
                b[i] = *(const short8*)&Bs[wc * 64 + i * 16 + l15][kk + l4 * 8];
#pragma unroll
            for (int mi = 0; mi < 4; ++mi)
#pragma unroll
                for (int ni = 0; ni < 4; ++ni)
                    acc[mi][ni] = __builtin_amdgcn_mfma_f32_16x16x32_bf16(
                        a[mi], b[ni], acc[mi][ni], 0, 0, 0);
        }
    }
    // epilogue: C/D layout col=lane&15, row=(lane>>4)*4+reg
#pragma unroll
    for (int mi = 0; mi < 4; ++mi) {
        int mb = row0 + wr * 64 + mi * 16 + l4 * 4;
        float dv[4];
#pragma unroll
        for (int r = 0; r < 4; ++r) dv[r] = (mb + r < M) ? dinv[mb + r] : 0.f;
#pragma unroll
        for (int ni = 0; ni < 4; ++ni) {
            int n = col0 + wc * 64 + ni * 16 + l15;
#pragma unroll
            for (int r = 0; r < 4; ++r) {
                if (mb + r < M)
                    hwb[(size_t)(mb + r) * 256 + n] = f2b(acc[mi][ni][r] * dv[r]);
            }
        }
    }
}

// ---------------- CSR aggregation (bf16 gathers, 8x unrolled): one wave per node ----------------
__global__ void k_agg(const unsigned short* __restrict__ hwb, float* __restrict__ agg,
                      const int* __restrict__ csr, const int* __restrict__ rs,
                      const int* __restrict__ cnt, const float* __restrict__ dinv,
                      const float* __restrict__ bias, int N) {
    int wave = threadIdx.x >> 6;
    int lane = threadIdx.x & 63;
    int n = blockIdx.x * 4 + wave;
    if (n >= N) return;
    float dn = dinv[n];
    int e = rs[n];
    int end = e + cnt[n];
    // self term (hwb already carries dinv[src])
    float4 acc = bf4_to_f4(((const ushort4*)(hwb + (size_t)n * HH))[lane]);
    for (; e + 8 <= end; e += 8) {
        int s0 = csr[e],     s1 = csr[e + 1], s2 = csr[e + 2], s3 = csr[e + 3];
        int s4 = csr[e + 4], s5 = csr[e + 5], s6 = csr[e + 6], s7 = csr[e + 7];
        float4 m0 = bf4_to_f4(((const ushort4*)(hwb + (size_t)s0 * HH))[lane]);
        float4 m1 = bf4_to_f4(((const ushort4*)(hwb + (size_t)s1 * HH))[lane]);
        float4 m2 = bf4_to_f4(((const ushort4*)(hwb + (size_t)s2 * HH))[lane]);
        float4 m3 = bf4_to_f4(((const ushort4*)(hwb + (size_t)s3 * HH))[lane]);
        float4 m4 = bf4_to_f4(((const ushort4*)(hwb + (size_t)s4 * HH))[lane]);
        float4 m5 = bf4_to_f4(((const ushort4*)(hwb + (size_t)s5 * HH))[lane]);
        float4 m6 = bf4_to_f4(((const ushort4*)(hwb + (size_t)s6 * HH))[lane]);
        float4 m7 = bf4_to_f4(((const ushort4*)(hwb + (size_t)s7 * HH))[lane]);
        acc.x += ((m0.x + m1.x) + (m2.x + m3.x)) + ((m4.x + m5.x) + (m6.x + m7.x));
        acc.y += ((m0.y + m1.y) + (m2.y + m3.y)) + ((m4.y + m5.y) + (m6.y + m7.y));
        acc.z += ((m0.z + m1.z) + (m2.z + m3.z)) + ((m4.z + m5.z) + (m6.z + m7.z));
        acc.w += ((m0.w + m1.w) + (m2.w + m3.w)) + ((m4.w + m5.w) + (m6.w + m7.w));
    }
    for (; e + 4 <= end; e += 4) {
        int s0 = csr[e], s1 = csr[e + 1], s2 = csr[e + 2], s3 = csr[e + 3];
        float4 m0 = bf4_to_f4(((const ushort4*)(hwb + (size_t)s0 * HH))[lane]);
        float4 m1 = bf4_to_f4(((const ushort4*)(hwb + (size_t)s1 * HH))[lane]);
        float4 m2 = bf4_to_f4(((const ushort4*)(hwb + (size_t)s2 * HH))[lane]);
        float4 m3 = bf4_to_f4(((const ushort4*)(hwb + (size_t)s3 * HH))[lane]);
        acc.x += (m0.x + m1.x) + (m2.x + m3.x);
        acc.y += (m0.y + m1.y) + (m2.y + m3.y);
        acc.z += (m0.z + m1.z) + (m2.z + m3.z);
        acc.w += (m0.w + m1.w) + (m2.w + m3.w);
    }
    for (; e < end; ++e) {
        int s = csr[e];
        float4 m = bf4_to_f4(((const ushort4*)(hwb + (size_t)s * HH))[lane]);
        acc.x += m.x; acc.y += m.y; acc.z += m.z; acc.w += m.w;
    }
    float4 b = ((const float4*)bias)[lane];
    float4 r;
    r.x = acc.x * dn + b.x; r.y = acc.y * dn + b.y;
    r.z = acc.z * dn + b.z; r.w = acc.w * dn + b.w;
    ((float4*)(agg + (size_t)n * HH))[lane] = r;
}

// ---------------- BN stats (col sum / sumsq), high-occupancy ----------------
__global__ __launch_bounds__(256) void k_bnstats(const float4* __restrict__ agg,
                                                 float* __restrict__ colsum,
                                                 float* __restrict__ colsq, int N) {
    __shared__ float4 ssum[4][64];
    __shared__ float4 ssq[4][64];
    int lane = threadIdx.x & 63;
    int wv = threadIdx.x >> 6;
    int rows_per = (N + gridDim.x - 1) / gridDim.x;
    int r0 = blockIdx.x * rows_per;
    int r1 = r0 + rows_per; if (r1 > N) r1 = N;
    float4 s = make_float4(0.f, 0.f, 0.f, 0.f);
    float4 s2 = make_float4(0.f, 0.f, 0.f, 0.f);
    for (int r = r0 + wv; r < r1; r += 4) {
        float4 v = agg[(size_t)r * 64 + lane];
        s.x += v.x; s.y += v.y; s.z += v.z; s.w += v.w;
        s2.x += v.x * v.x; s2.y += v.y * v.y; s2.z += v.z * v.z; s2.w += v.w * v.w;
    }
    ssum[wv][lane] = s;
    ssq[wv][lane] = s2;
    __syncthreads();
    int j = lane * 4;
    if (wv == 0) {
        float4 a = ssum[0][lane], b = ssum[1][lane], c = ssum[2][lane], d = ssum[3][lane];
        atomicAdd(&colsum[j + 0], a.x + b.x + c.x + d.x);
        atomicAdd(&colsum[j + 1], a.y + b.y + c.y + d.y);
        atomicAdd(&colsum[j + 2], a.z + b.z + c.z + d.z);
        atomicAdd(&colsum[j + 3], a.w + b.w + c.w + d.w);
    } else if (wv == 1) {
        float4 a = ssq[0][lane], b = ssq[1][lane], c = ssq[2][lane], d = ssq[3][lane];
        atomicAdd(&colsq[j + 0], a.x + b.x + c.x + d.x);
        atomicAdd(&colsq[j + 1], a.y + b.y + c.y + d.y);
        atomicAdd(&colsq[j + 2], a.z + b.z + c.z + d.z);
        atomicAdd(&colsq[j + 3], a.w + b.w + c.w + d.w);
    }
}

// ---------------- BN + ReLU + residual (bf16 state in hb) ----------------
__global__ void k_epi(const float4* __restrict__ agg, ushort4* __restrict__ hb,
                      const float4* __restrict__ colsum, const float4* __restrict__ colsq,
                      const float4* __restrict__ g4, const float4* __restrict__ b4,
                      int total, float invN) {
    int idx = blockIdx.x * 256 + threadIdx.x;
    if (idx >= total) return;
    int q = idx & 63;
    float4 a = agg[idx];
    float4 s = colsum[q], s2 = colsq[q], g = g4[q], b = b4[q];
    float4 hv = bf4_to_f4(hb[idx]);
    float mu, var, v;
    mu = s.x * invN; var = s2.x * invN - mu * mu;
    v = (a.x - mu) * rsqrtf(var + EPSF) * g.x + b.x; hv.x += fmaxf(v, 0.f);
    mu = s.y * invN; var = s2.y * invN - mu * mu;
    v = (a.y - mu) * rsqrtf(var + EPSF) * g.y + b.y; hv.y += fmaxf(v, 0.f);
    mu = s.z * invN; var = s2.z * invN - mu * mu;
    v = (a.z - mu) * rsqrtf(var + EPSF) * g.z + b.z; hv.z += fmaxf(v, 0.f);
    mu = s.w * invN; var = s2.w * invN - mu * mu;
    v = (a.w - mu) * rsqrtf(var + EPSF) * g.w + b.w; hv.w += fmaxf(v, 0.f);
    ushort4 u;
    u.x = f2b(hv.x); u.y = f2b(hv.y); u.z = f2b(hv.z); u.w = f2b(hv.w);
    hb[idx] = u;
}

// ---------------- graph boundaries (batch is sorted) ----------------
__global__ void k_ginit(int* __restrict__ gstart, int G, int N) {
    int g = blockIdx.x * 256 + threadIdx.x;
    if (g <= G) gstart[g] = N;
}

__global__ void k_gbound(const int* __restrict__ batch, int* __restrict__ gstart, int N) {
    int n = blockIdx.x * 256 + threadIdx.x;
    if (n >= N) return;
    int b = batch[n];
    int prev = (n == 0) ? -1 : batch[n - 1];
    for (int g = prev + 1; g <= b; ++g) gstart[g] = n;
}

// ---------------- segmented mean pool (bf16 in): one block (4 waves) per graph ----------------
__global__ void k_pool(const unsigned short* __restrict__ hb, const int* __restrict__ gstart,
                       float* __restrict__ pooled) {
    __shared__ float4 sm[4][64];
    int g = blockIdx.x;
    int t = threadIdx.x;
    int lane = t & 63, wv = t >> 6;
    int s = gstart[g], e = gstart[g + 1];
    float4 acc = make_float4(0.f, 0.f, 0.f, 0.f);
    for (int n = s + wv; n < e; n += 4) {
        float4 v = bf4_to_f4(((const ushort4*)(hb + (size_t)n * HH))[lane]);
        acc.x += v.x; acc.y += v.y; acc.z += v.z; acc.w += v.w;
    }
    sm[wv][lane] = acc;
    __syncthreads();
    if (wv == 0) {
        float4 a = sm[0][lane], b = sm[1][lane], c = sm[2][lane], d = sm[3][lane];
        float inv = 1.0f / fmaxf((float)(e - s), 1.0f);
        float4 r;
        r.x = (a.x + b.x + c.x + d.x) * inv;
        r.y = (a.y + b.y + c.y + d.y) * inv;
        r.z = (a.z + b.z + c.z + d.z) * inv;
        r.w = (a.w + b.w + c.w + d.w) * inv;
        ((float4*)pooled)[(size_t)g * 64 + lane] = r;
    }
}

// ---------------- MLP head: one block per graph ----------------
__global__ void k_head(const float* __restrict__ pooled,
                       const float* __restrict__ W1, const float* __restrict__ b1,
                       const float* __restrict__ W2, const float* __restrict__ b2,
                       float* __restrict__ out) {
    __shared__ float prow[256];
    __shared__ float hred[128];
    int g = blockIdx.x, t = threadIdx.x;  // 128 threads
    prow[t] = pooled[(size_t)g * HH + t];
    prow[t + 128] = pooled[(size_t)g * HH + t + 128];
    __syncthreads();
    float acc = b1[t];
    for (int k = 0; k < HH; ++k) acc += prow[k] * W1[(size_t)k * 128 + t];
    float hid = fmaxf(acc, 0.f);
    hred[t] = hid * W2[t];
    __syncthreads();
    for (int off = 64; off > 0; off >>= 1) {
        if (t < off) hred[t] += hred[t + off];
        __syncthreads();
    }
    if (t == 0) out[g] = hred[0] + b2[0];
}

extern "C" void kernel_launch(void* const* d_in, const int* in_sizes, int n_in,
                              void* d_out, int out_size, void* d_ws, size_t ws_size,
                              hipStream_t stream) {
    const int* x        = (const int*)d_in[0];
    const int* tags     = (const int*)d_in[1];
    const int* ei       = (const int*)d_in[2];
    const int* batch    = (const int*)d_in[3];
    const float* atom_e = (const float*)d_in[4];
    const float* tag_e  = (const float*)d_in[5];
    const float* Wp     = (const float*)d_in[6];
    const float* bp     = (const float*)d_in[7];
    const float* gcn_W  = (const float*)d_in[8];
    const float* gcn_b  = (const float*)d_in[9];
    const float* bn_g   = (const float*)d_in[10];
    const float* bn_b   = (const float*)d_in[11];
    const float* W1     = (const float*)d_in[12];
    const float* b1     = (const float*)d_in[13];
    const float* W2     = (const float*)d_in[14];
    const float* b2     = (const float*)d_in[15];
    float* out = (float*)d_out;

    const int N = NN, E = EE, G = GG, H = HH;
    const int Mpad = ((N + 127) / 128) * 128;  // 50048

    char* p = (char*)d_ws;
    auto alloc = [&](size_t bytes) {
        void* r = (void*)p;
        p += (bytes + 255) & ~(size_t)255;
        return r;
    };
    unsigned short* hb  = (unsigned short*)alloc((size_t)Mpad * H * 2);
    unsigned short* hwb = (unsigned short*)alloc((size_t)Mpad * H * 2);
    unsigned short* Wt  = (unsigned short*)alloc((size_t)LL * H * H * 2);
    float* agg  = (float*)alloc((size_t)N * H * 4);
    float* dinv = (float*)alloc((size_t)N * 4);
    int* cnt    = (int*)alloc((size_t)N * 4);
    int* rs     = (int*)alloc((size_t)N * 4);
    int* cur    = (int*)alloc((size_t)N * 4);
    int* csr    = (int*)alloc((size_t)E * 4);
    int* bsum   = (int*)alloc(64 * 4);
    float* aref = (float*)alloc(100 * (size_t)H * 4);
    float* tref = (float*)alloc(3 * (size_t)H * 4);
    float* cstat= (float*)alloc(2 * (size_t)H * 4);  // colsum | colsq
    int* gstart = (int*)alloc((size_t)(G + 1) * 4);
    float* pooled = (float*)alloc((size_t)G * H * 4);

    const int* src = ei;
    const int* dst = ei + E;

    hipMemsetAsync(cnt, 0, (size_t)N * 4, stream);
    hipMemsetAsync(cur, 0, (size_t)N * 4, stream);

    k_degree<<<(E + 255) / 256, 256, 0, stream>>>(dst, cnt, E);
    k_dinv<<<(N + 255) / 256, 256, 0, stream>>>(cnt, dinv, N);

    int nb = (N + 1023) / 1024;
    k_scan1<<<nb, 1024, 0, stream>>>(cnt, rs, bsum, N);
    k_scan2<<<1, 64, 0, stream>>>(bsum, nb);
    k_scan3<<<(N + 255) / 256, 256, 0, stream>>>(rs, cnt, bsum, N);
    k_scatter<<<(E + 255) / 256, 256, 0, stream>>>(src, dst, rs, cur, csr, E);

    k_ginit<<<(G + 256) / 256, 256, 0, stream>>>(gstart, G, N);
    k_gbound<<<(N + 255) / 256, 256, 0, stream>>>(batch, gstart, N);

    k_wprep<<<dim3(64, LL), 256, 0, stream>>>(gcn_W, Wt);
    k_proj<<<103, 256, 0, stream>>>(atom_e, tag_e, Wp, bp, aref, tref);
    k_h0<<<N, 64, 0, stream>>>(x, tags, aref, tref, hb, N);

    for (int l = 0; l < LL; ++l) {
        k_gemm<<<dim3(2, Mpad / 128), 256, 0, stream>>>(
            hb, Wt + (size_t)l * H * H, dinv, hwb, N);
        k_agg<<<(N + 3) / 4, 256, 0, stream>>>(hwb, agg, csr, rs, cnt, dinv,
                                               gcn_b + (size_t)l * H, N);
        hipMemsetAsync(cstat, 0, 2 * (size_t)H * 4, stream);
        k_bnstats<<<512, 256, 0, stream>>>((const float4*)agg, cstat, cstat + H, N);
        k_epi<<<(N * 64 + 255) / 256, 256, 0, stream>>>(
            (const float4*)agg, (ushort4*)hb,
            (const float4*)cstat, (const float4*)(cstat + H),
            (const float4*)(bn_g + (size_t)l * H), (const float4*)(bn_b + (size_t)l * H),
            N * 64, 1.0f / (float)N);
    }

    k_pool<<<G, 256, 0, stream>>>(hb, gstart, pooled);
    k_head<<<G, 128, 0, stream>>>(pooled, W1, b1, W2, b2, out);
}